// Round 13
// baseline (443.401 us; speedup 1.0000x reference)
//
#include <hip/hip_runtime.h>
#include <hip/hip_bf16.h>
#include <math.h>

#define HWN 4096      // 64*64
#define DCH 256
#define EPSV 1e-5f

typedef unsigned short u16;
typedef __attribute__((ext_vector_type(8))) short short8b;   // 8 bf16 payload
typedef __attribute__((ext_vector_type(4))) float fx4;
typedef __attribute__((ext_vector_type(8))) unsigned short u16x8;

static __device__ inline u16 f2bf(float f) {
  __hip_bfloat16 h = __float2bfloat16(f);
  return *reinterpret_cast<u16*>(&h);
}
static __device__ inline float bf2f(u16 u) {
  unsigned int v = ((unsigned int)u) << 16;
  return __uint_as_float(v);
}

// ---------------- batched NCHW f32 -> CHWc bf16 (3 branches x 2 batch) ----------------
__global__ __launch_bounds__(256) void t_chwc3_k(const float* __restrict__ i0p,
    const float* __restrict__ i1p, const float* __restrict__ i2p,
    u16* __restrict__ out) {
  __shared__ float tl[32][257];
  const int p0 = blockIdx.x * 256, cic = blockIdx.y;
  const int z = blockIdx.z;             // br*2 + b
  const int br = z >> 1, b = z & 1;
  const float* in = (br == 0) ? i0p : ((br == 1) ? i1p : i2p);
  const int t = threadIdx.x;
  const float* ip = in + ((size_t)(b * 512 + cic * 32)) * HWN + p0;
#pragma unroll
  for (int r = 0; r < 32; ++r) tl[r][t] = ip[(size_t)r * HWN + t];
  __syncthreads();
  u16* op = out + ((size_t)((z * 16 + cic)) * HWN + p0 + t) * 32;
#pragma unroll
  for (int g = 0; g < 4; ++g) {
    u16x8 o;
#pragma unroll
    for (int j = 0; j < 8; ++j) o[j] = f2bf(tl[g * 8 + j][t]);
    *reinterpret_cast<u16x8*>(op + g * 8) = o;
  }
}

// ---------------- weights OIHW f32 -> fragment-packed bf16 ----------------
template<int CIN, int COUT>
__global__ __launch_bounds__(256) void wpack_k(const float* __restrict__ w0,
    const float* __restrict__ w1, const float* __restrict__ w2,
    u16* __restrict__ wp) {
  constexpr int NCIC = CIN / 32, NCOG = COUT / 16;
  const int br = blockIdx.y;
  const float* w = (br == 0) ? w0 : ((br == 1) ? w1 : w2);
  u16* wpb = wp + (size_t)br * 9 * NCIC * NCOG * 512;
  const int cog = blockIdx.x % NCOG, cic = blockIdx.x / NCOG;
  __shared__ float ws_[16 * 32 * 9];    // 18 KB
  const int t = threadIdx.x;
  const float* src = w + ((size_t)(cog * 16) * CIN + cic * 32) * 9;
  for (int i = t; i < 4608; i += 256) {
    int co = i / 288, r = i % 288;
    ws_[i] = src[(size_t)co * CIN * 9 + r];
  }
  __syncthreads();
  const size_t tapstride = (size_t)NCIC * NCOG * 512;
  const size_t base = ((size_t)cic * NCOG + cog) * 512;
#pragma unroll
  for (int tap = 0; tap < 9; ++tap) {
#pragma unroll
    for (int e0 = 0; e0 < 512; e0 += 256) {
      int e = e0 + t;
      int kg = e >> 7, m = (e >> 3) & 15, j = e & 7;
      wpb[tap * tapstride + base + e] = f2bf(ws_[m * 288 + (kg * 8 + j) * 9 + tap]);
    }
  }
}

// ---------------- split-K MFMA conv 3x3 pad 1, A+B in LDS ----------------
// wave = 64px (one image row) x COW co; block = 4 waves = 4 rows.
// R6 grid mapping. A: 6 halo rows, PXS=32 u16/pixel, AROW staggered +8 u16 so
// successive rows start 4 banks apart (cross-wave decorrelation); contiguous
// A-writes; A+B register-prefetched and written between barriers.
template<int CIN, int COUT, int SPLIT, int COW, int WPE, bool BF16OUT>
__global__ __launch_bounds__(256, WPE) void convlds4_k(
    const u16* __restrict__ xt, const u16* __restrict__ wp,
    void* __restrict__ outv) {
  constexpr int NCIC = CIN / 32;
  constexpr int NCO = COUT / COW;
  constexpr int NWT = COW / 16;
  constexpr int CICPS = NCIC / SPLIT;
  constexpr int NST = CICPS * 3;
  constexpr int TAPB = COW * 32;          // u16 per B tap
  constexpr int WSH = TAPB / 4;           // u16 per wave per tap
  constexpr int RNDS = WSH / 512;         // 1KB rounds per wave per tap
  constexpr int AROW = 66 * 32 + 8;       // u16 per padded A row (bank-staggered)
  constexpr size_t OUTEL = (size_t)2 * COUT * HWN;
  __shared__ u16 bl[3 * TAPB];
  __shared__ u16 al[6 * AROW];

  const int br = blockIdx.y;
  xt += (size_t)br * 2 * NCIC * HWN * 32;
  wp += (size_t)br * 9 * NCIC * (COUT / 16) * 512;

  int g = blockIdx.x;
  const int cpx = (int)gridDim.x >> 3;
  g = (g & 7) * cpx + (g >> 3);
  const int s = g / (32 * NCO);
  const int rem = g % (32 * NCO);
  const int rt = rem / NCO;
  const int cob = (rem % NCO) * COW;

  const int wv = threadIdx.x >> 6, lane = threadIdx.x & 63;
  const int b = (rt * 4) >> 6;           // block-uniform batch
  const int h0 = (rt * 4) & 63;          // block's first image row
  const int h = h0 + wv;
  const int m = lane & 15, kg = lane >> 4;
  const int cic0 = s * CICPS;
  const int t = threadIdx.x;

  fx4 acc[4][NWT];
#pragma unroll
  for (int i = 0; i < 4; ++i)
#pragma unroll
    for (int jn = 0; jn < NWT; ++jn) acc[i][jn] = (fx4){0.f, 0.f, 0.f, 0.f};

  const u16x8 zero16 = (u16x8){0, 0, 0, 0, 0, 0, 0, 0};
  const int lds_lane = wv * WSH + lane * 8;        // B write slot

  // A global-load helper (6 rows into regs)
  auto load_a = [&](int cic, u16x8* dst) {
    const u16* xc = xt + ((size_t)(b * NCIC + cic)) * HWN * 32;
#pragma unroll
    for (int r = 0; r < 6; ++r) {
      const int hl = h0 - 1 + r;
      u16x8 v = zero16;
      if ((unsigned)hl < 64u)
        v = *reinterpret_cast<const u16x8*>(xc + (size_t)hl * 2048 + t * 8);
      dst[r] = v;
    }
  };
  auto write_a = [&](const u16x8* src) {   // contiguous per row: conflict-free
#pragma unroll
    for (int r = 0; r < 6; ++r)
      *reinterpret_cast<u16x8*>(&al[r * AROW + 32 + t * 8]) = src[r];
  };

  // prologue: zero pads (persist), stage A(cic0) + B(stage 0)
  if (t < 48) {
    int r = t >> 3, side = (t >> 2) & 1, sl = t & 3;
    *reinterpret_cast<u16x8*>(&al[r * AROW + (side ? 65 * 32 : 0) + sl * 8]) = zero16;
  }
  {
    u16x8 a0[6];
    load_a(cic0, a0);
    write_a(a0);
#pragma unroll
    for (int t3 = 0; t3 < 3; ++t3) {
      const u16* srcb = wp + (((size_t)t3 * NCIC + cic0) * (COUT / 16) + (cob >> 4)) * 512;
#pragma unroll
      for (int r = 0; r < RNDS; ++r)
        *reinterpret_cast<u16x8*>(&bl[t3 * TAPB + lds_lane + r * 512]) =
            *reinterpret_cast<const u16x8*>(srcb + lds_lane + r * 512);
    }
  }
  __syncthreads();

#pragma unroll 1
  for (int st = 0; st < NST; ++st) {
    const bool hasnext = (st + 1 < NST);
    const int ty = st % 3;
    const bool newcic = hasnext && (ty == 2);
    // prefetch next-stage B (and A on cic boundary) into registers
    u16x8 stg[3][RNDS];
    u16x8 astg[6];
    if (hasnext) {
      const int cicn = cic0 + (st + 1) / 3, tyn = (st + 1) % 3;
#pragma unroll
      for (int t3 = 0; t3 < 3; ++t3) {
        const int tap = tyn * 3 + t3;
        const u16* srcb = wp + (((size_t)tap * NCIC + cicn) * (COUT / 16) + (cob >> 4)) * 512;
#pragma unroll
        for (int r = 0; r < RNDS; ++r)
          stg[t3][r] = *reinterpret_cast<const u16x8*>(srcb + lds_lane + r * 512);
      }
      if (newcic) load_a(cicn, astg);
    }
    // compute current stage (A and B both from LDS; no branches)
    const u16* arow = al + (wv + ty) * AROW + kg * 8;
#pragma unroll
    for (int tx = 0; tx < 3; ++tx) {
      short8b a[4];
#pragma unroll
      for (int mt = 0; mt < 4; ++mt)
        a[mt] = *reinterpret_cast<const short8b*>(arow + (mt * 16 + m + tx) * 32);
      short8b bb[NWT];
#pragma unroll
      for (int nt = 0; nt < NWT; ++nt)
        bb[nt] = *reinterpret_cast<const short8b*>(&bl[tx * TAPB + nt * 512 + lane * 8]);
#pragma unroll
      for (int mt = 0; mt < 4; ++mt)
#pragma unroll
        for (int nt = 0; nt < NWT; ++nt)
          acc[mt][nt] = __builtin_amdgcn_mfma_f32_16x16x32_bf16(a[mt], bb[nt], acc[mt][nt], 0, 0, 0);
    }
    __syncthreads();                     // all LDS reads done
    if (hasnext) {
      if (newcic) write_a(astg);
#pragma unroll
      for (int t3 = 0; t3 < 3; ++t3)
#pragma unroll
        for (int r = 0; r < RNDS; ++r)
          *reinterpret_cast<u16x8*>(&bl[t3 * TAPB + lds_lane + r * 512]) = stg[t3][r];
      __syncthreads();                   // new A+B visible
    }
  }

#pragma unroll
  for (int mt = 0; mt < 4; ++mt)
#pragma unroll
    for (int nt = 0; nt < NWT; ++nt) {
      int co = cob + nt * 16 + m;
      size_t idx = ((size_t)(b * COUT + co)) * HWN + h * 64 + mt * 16 + kg * 4;
      if (BF16OUT) {
        u16* op = (u16*)outv + (size_t)(br * SPLIT + s) * OUTEL + idx;
        ushort4 o;
        o.x = f2bf(acc[mt][nt][0]); o.y = f2bf(acc[mt][nt][1]);
        o.z = f2bf(acc[mt][nt][2]); o.w = f2bf(acc[mt][nt][3]);
        *reinterpret_cast<ushort4*>(op) = o;
      } else {
        float* op = (float*)outv + (size_t)(br * SPLIT + s) * OUTEL + idx;
        *reinterpret_cast<fx4*>(op) = acc[mt][nt];
      }
    }
}

// ---------------- fused smooth tail: 4-slab reduce + BN2d stats + apply + relu -------
__global__ __launch_bounds__(256) void bnall_k(const u16* __restrict__ slab,
    float* __restrict__ dout, const float* __restrict__ gm,
    const float* __restrict__ bt) {
  const int o = blockIdx.x;
  const size_t el = (size_t)2 * 512 * HWN;
  const int t = threadIdx.x;
  float y[2][2][8];
  float s = 0.f, ss = 0.f;
#pragma unroll
  for (int b = 0; b < 2; ++b)
#pragma unroll
    for (int c = 0; c < 2; ++c) {
      const size_t base = ((size_t)(b * 512 + o)) * HWN + c * 2048 + t * 8;
      u16x8 v0 = *reinterpret_cast<const u16x8*>(slab + base);
      u16x8 v1 = *reinterpret_cast<const u16x8*>(slab + el + base);
      u16x8 v2 = *reinterpret_cast<const u16x8*>(slab + 2 * el + base);
      u16x8 v3 = *reinterpret_cast<const u16x8*>(slab + 3 * el + base);
#pragma unroll
      for (int j = 0; j < 8; ++j) {
        float yv = (bf2f(v0[j]) + bf2f(v1[j])) + (bf2f(v2[j]) + bf2f(v3[j]));
        y[b][c][j] = yv; s += yv; ss = fmaf(yv, yv, ss);
      }
    }
  __shared__ float rs[4], rss[4], fin[2];
  for (int off = 32; off; off >>= 1) { s += __shfl_down(s, off); ss += __shfl_down(ss, off); }
  int lane = t & 63, wid = t >> 6;
  if (lane == 0) { rs[wid] = s; rss[wid] = ss; }
  __syncthreads();
  if (t == 0) {
    float S = rs[0] + rs[1] + rs[2] + rs[3];
    float SS = rss[0] + rss[1] + rss[2] + rss[3];
    float mean = S / (2 * HWN);
    float var = SS / (2 * HWN) - mean * mean;
    fin[0] = mean;
    fin[1] = 1.f / sqrtf(var + EPSV);
  }
  __syncthreads();
  const float mean = fin[0], giv = fin[1] * gm[o], be = bt[o];
#pragma unroll
  for (int b = 0; b < 2; ++b)
#pragma unroll
    for (int c = 0; c < 2; ++c) {
      const size_t base = ((size_t)(b * 512 + o)) * HWN + c * 2048 + t * 8;
      fx4 o0, o1;
#pragma unroll
      for (int j = 0; j < 4; ++j)
        o0[j] = fmaxf(fmaf(y[b][c][j] - mean, giv, be), 0.f);
#pragma unroll
      for (int j = 0; j < 4; ++j)
        o1[j] = fmaxf(fmaf(y[b][c][4 + j] - mean, giv, be), 0.f);
      *reinterpret_cast<fx4*>(dout + base) = o0;
      *reinterpret_cast<fx4*>(dout + base + 4) = o1;
    }
}

// ---------------- batched AB + Ck precompute ----------------
__global__ __launch_bounds__(256) void prep3_k(
    const float* __restrict__ sc0, const float* __restrict__ sc1, const float* __restrict__ sc2,
    const float* __restrict__ cw0, const float* __restrict__ cw1, const float* __restrict__ cw2,
    float2* __restrict__ AB, float* __restrict__ Ck) {
  const int br = blockIdx.y;
  const int K = 8 << br;
  const int k = blockIdx.x;
  if (k >= K) return;
  const float* sc = (br == 0) ? sc0 : ((br == 1) ? sc1 : sc2);
  const float* cw = (br == 0) ? cw0 : ((br == 1) ? cw1 : cw2);
  float2* ABb = AB + 2048 * ((1 << br) - 1);
  float* Ckb = Ck + 8 * ((1 << br) - 1);
  const int d = threadIdx.x;
  float s = sc[d * K + k];
  float a = s * s;
  float c = cw[k * DCH + d];
  ABb[d * K + k] = make_float2(a, c * a);
  float tt = c * s;
  tt = tt * tt;
  __shared__ float red[4];
  for (int off = 32; off; off >>= 1) tt += __shfl_down(tt, off);
  int lane = threadIdx.x & 63, wid = threadIdx.x >> 6;
  if (lane == 0) red[wid] = tt;
  __syncthreads();
  if (threadIdx.x == 0) Ckb[k] = red[0] + red[1] + red[2] + red[3];
}

// ---------------- score body: 4-slab reduce + scores + softmax ----------------
template<int K>
static __device__ void score_body(int b, float* sm, const u16* __restrict__ sl,
    const float2* __restrict__ AB, const float* __restrict__ Ck,
    float* __restrict__ Qt, float* __restrict__ Qsp) {
  const size_t XEL = (size_t)2 * DCH * HWN;
  const int lane = threadIdx.x & 63;
  const int g = threadIdx.x >> 6;
  const int n = blockIdx.x * 64 + lane;
  const size_t bbase = ((size_t)b * DCH) * HWN + n;
  float s_[K];
#pragma unroll
  for (int k = 0; k < K; ++k) s_[k] = 0.f;
  for (int d = g * 64; d < g * 64 + 64; ++d) {
    const size_t ofs = bbase + (size_t)d * HWN;
    float xv = (bf2f(sl[ofs]) + bf2f(sl[XEL + ofs]))
             + (bf2f(sl[2 * XEL + ofs]) + bf2f(sl[3 * XEL + ofs]));
    float x2 = xv * xv;
    float xm = -2.f * xv;
    const float2* abp = AB + d * K;
#pragma unroll
    for (int k = 0; k < K; ++k) {
      float2 ab = abp[k];
      s_[k] = fmaf(x2, ab.x, s_[k]);
      s_[k] = fmaf(xm, ab.y, s_[k]);
    }
  }
  float* smr = sm + (g * 64 + lane) * (K + 1);
#pragma unroll
  for (int k = 0; k < K; ++k) smr[k] = s_[k];
  __syncthreads();
  if (g == 0) {
    const float* r0 = sm + lane * (K + 1);
    const float* r1 = sm + (64 + lane) * (K + 1);
    const float* r2 = sm + (128 + lane) * (K + 1);
    const float* r3 = sm + (192 + lane) * (K + 1);
    float mx = -1e30f;
#pragma unroll
    for (int k = 0; k < K; ++k) {
      float v = (r0[k] + r1[k]) + (r2[k] + r3[k]);
      s_[k] = -0.5f * (v + Ck[k]);
      mx = fmaxf(mx, s_[k]);
    }
    float sum = 0.f;
#pragma unroll
    for (int k = 0; k < K; ++k) { float e = expf(s_[k] - mx); s_[k] = e; sum += e; }
    float inv = 1.f / sum;
#pragma unroll
    for (int k = 0; k < K; ++k) {
      float v = s_[k] * inv;
      Qt[((size_t)(b * K + k)) * HWN + n] = v;
      for (int off = 32; off; off >>= 1) v += __shfl_down(v, off);
      if (lane == 0) Qsp[((size_t)(b * K + k)) * 64 + blockIdx.x] = v;
    }
  }
}

__global__ __launch_bounds__(256) void score3_k(const u16* __restrict__ bslab,
    const float2* __restrict__ AB3, const float* __restrict__ Ck3,
    float* __restrict__ Qt3, float* __restrict__ Qsp3) {
  __shared__ float sm[4 * 64 * 33];
  const int z = blockIdx.y, br = z >> 1, b = z & 1;
  const size_t XEL = (size_t)2 * DCH * HWN;
  const u16* sl = bslab + (size_t)br * 4 * XEL;
  if (br == 0)
    score_body<8>(b, sm, sl, AB3, Ck3, Qt3, Qsp3);
  else if (br == 1)
    score_body<16>(b, sm, sl, AB3 + 2048, Ck3 + 8, Qt3 + 65536, Qsp3 + 1024);
  else
    score_body<32>(b, sm, sl, AB3 + 6144, Ck3 + 24, Qt3 + 196608, Qsp3 + 3072);
}

// ---------------- mmul partials body (reads 4 bf16 slabs) ----------------
template<int K>
static __device__ void mmulp_body(int b, float* xs, float* pw,
    const u16* __restrict__ sl, const float* __restrict__ Qt,
    float* __restrict__ Mp) {
  const size_t XEL = (size_t)2 * DCH * HWN;
  const int d = blockIdx.x, nch = blockIdx.y;
  const int t = threadIdx.x;
  const size_t ofs = ((size_t)(b * DCH + d)) * HWN + nch * 512 + t;
  xs[t] = (bf2f(sl[ofs]) + bf2f(sl[XEL + ofs]))
        + (bf2f(sl[2 * XEL + ofs]) + bf2f(sl[3 * XEL + ofs]));
  xs[t + 256] = (bf2f(sl[ofs + 256]) + bf2f(sl[XEL + ofs + 256]))
              + (bf2f(sl[2 * XEL + ofs + 256]) + bf2f(sl[3 * XEL + ofs + 256]));
  __syncthreads();
  const int lane = t & 63, wid = t >> 6;
#pragma unroll
  for (int k = 0; k < K; ++k) {
    const float* qp = Qt + ((size_t)(b * K + k)) * HWN + nch * 512;
    float s = fmaf(xs[t], qp[t], xs[t + 256] * qp[t + 256]);
    for (int off = 32; off; off >>= 1) s += __shfl_down(s, off);
    if (lane == 0) pw[wid * 33 + k] = s;
  }
  __syncthreads();
  if (t < K)
    Mp[(((size_t)(b * DCH + d)) * K + t) * 8 + nch] =
        (pw[t] + pw[33 + t]) + (pw[66 + t] + pw[99 + t]);
}

__global__ __launch_bounds__(256) void mmulp3_k(const u16* __restrict__ bslab,
    const float* __restrict__ Qt3, float* __restrict__ Mp3) {
  __shared__ float xs[512];
  __shared__ float pw[4 * 33];
  const int z = blockIdx.z, br = z >> 1, b = z & 1;
  const size_t XEL = (size_t)2 * DCH * HWN;
  const u16* sl = bslab + (size_t)br * 4 * XEL;
  if (br == 0)
    mmulp_body<8>(b, xs, pw, sl, Qt3, Mp3);
  else if (br == 1)
    mmulp_body<16>(b, xs, pw, sl, Qt3 + 65536, Mp3 + 32768);
  else
    mmulp_body<32>(b, xs, pw, sl, Qt3 + 196608, Mp3 + 98304);
}

// ---------------- fuse1 body: Qsp/Mp reduce + Z + L2norm + adj + support + relu ------
template<int K>
static __device__ void fuse1_body(int b, float* buf, const float* __restrict__ Mp,
    const float* __restrict__ Qsp, const float* __restrict__ sc,
    const float* __restrict__ cw, const float* __restrict__ Wm,
    float* __restrict__ Graw) {
  float* zl = buf;
  float* adj = zl + DCH * K;
  float* rn = adj + K * K;
  float* qsl = rn + K;
  const int t = threadIdx.x;
  if (t < K) {
    const float* qp = Qsp + ((size_t)(b * K + t)) * 64;
    float s = 0.f;
    for (int i = 0; i < 64; ++i) s += qp[i];
    qsl[t] = s;
  }
  __syncthreads();
#pragma unroll
  for (int k = 0; k < K; ++k) {
    const float* mp = Mp + (((size_t)(b * DCH + t)) * K + k) * 8;
    fx4 p0 = *reinterpret_cast<const fx4*>(mp);
    fx4 p1 = *reinterpret_cast<const fx4*>(mp + 4);
    float mm = ((p0[0] + p0[1]) + (p0[2] + p0[3])) + ((p1[0] + p1[1]) + (p1[2] + p1[3]));
    float qs = qsl[k];
    zl[t * K + k] = sc[t * K + k] * (mm - cw[k * DCH + t] * qs) / qs;
  }
  __syncthreads();
  if (t < K) {
    float s = 0.f;
    for (int i = 0; i < DCH; ++i) { float v = zl[i * K + t]; s = fmaf(v, v, s); }
    rn[t] = 1.f / sqrtf(s);
  }
  __syncthreads();
#pragma unroll
  for (int k = 0; k < K; ++k) zl[t * K + k] *= rn[k];
  __syncthreads();
  for (int p = t; p < K * K; p += 256) {
    int k = p / K, l = p % K;
    float s = 0.f;
    for (int i = 0; i < DCH; ++i) s = fmaf(zl[i * K + k], zl[i * K + l], s);
    adj[p] = s;
  }
  __syncthreads();
  float sup[K];
#pragma unroll
  for (int k = 0; k < K; ++k) sup[k] = 0.f;
  const float* wr = Wm + (size_t)t * DCH;
  for (int jj = 0; jj < DCH; ++jj) {
    float wv = wr[jj];
#pragma unroll
    for (int k = 0; k < K; ++k) sup[k] = fmaf(wv, zl[jj * K + k], sup[k]);
  }
#pragma unroll
  for (int l = 0; l < K; ++l) {
    float s = 0.f;
#pragma unroll
    for (int k = 0; k < K; ++k) s = fmaf(sup[k], adj[k * K + l], s);
    Graw[((size_t)(b * DCH + t)) * K + l] = fmaxf(s, 0.f);
  }
}

__global__ __launch_bounds__(256) void fuse13_k(const float* __restrict__ Mp3,
    const float* __restrict__ Qsp3,
    const float* __restrict__ sc0, const float* __restrict__ sc1, const float* __restrict__ sc2,
    const float* __restrict__ cw0, const float* __restrict__ cw1, const float* __restrict__ cw2,
    const float* __restrict__ wm0, const float* __restrict__ wm1, const float* __restrict__ wm2,
    float* __restrict__ Graw3) {
  __shared__ float buf[DCH * 32 + 32 * 32 + 64];
  const int z = blockIdx.x, br = z >> 1, b = z & 1;
  if (br == 0)
    fuse1_body<8>(b, buf, Mp3, Qsp3, sc0, cw0, wm0, Graw3);
  else if (br == 1)
    fuse1_body<16>(b, buf, Mp3 + 32768, Qsp3 + 1024, sc1, cw1, wm1, Graw3 + 4096);
  else
    fuse1_body<32>(b, buf, Mp3 + 98304, Qsp3 + 3072, sc2, cw2, wm2, Graw3 + 12288);
}

// ---------------- fuse2 body: BN1d (redundant per block) + EG ----------------
template<int K>
static __device__ void fuse2_body(int b, int ob, float* gl,
    const float* __restrict__ Graw, const float* __restrict__ gamma,
    const float* __restrict__ beta, const float* __restrict__ E,
    float* __restrict__ EG) {
  const int t = threadIdx.x;
  {
    const int d = t;
    float s = 0.f, ss = 0.f;
#pragma unroll
    for (int b2 = 0; b2 < 2; ++b2)
#pragma unroll
      for (int l = 0; l < K; ++l) {
        float v = Graw[((size_t)(b2 * DCH + d)) * K + l];
        s += v; ss = fmaf(v, v, ss);
      }
    const float invn = 1.f / (2 * K);
    float mean = s * invn;
    float var  = ss * invn - mean * mean;
    float giv  = gamma[d] / sqrtf(var + EPSV);
    float be   = beta[d];
#pragma unroll
    for (int l = 0; l < K; ++l) {
      float v = Graw[((size_t)(b * DCH + d)) * K + l];
      gl[d * K + l] = fmaf(v - mean, giv, be);
    }
  }
  __syncthreads();
  const int o = ob * 256 + t;
  float a[K];
#pragma unroll
  for (int k = 0; k < K; ++k) a[k] = 0.f;
  const fx4* e4 = reinterpret_cast<const fx4*>(E + (size_t)o * DCH);
  for (int d4 = 0; d4 < 64; ++d4) {
    fx4 v = e4[d4];
#pragma unroll
    for (int j = 0; j < 4; ++j) {
      float vv = v[j];
#pragma unroll
      for (int k = 0; k < K; ++k)
        a[k] = fmaf(vv, gl[(d4 * 4 + j) * K + k], a[k]);
    }
  }
#pragma unroll
  for (int k = 0; k < K; ++k)
    EG[((size_t)(b * 512 + o)) * K + k] = a[k];
}

__global__ __launch_bounds__(256) void fuse23_k(const float* __restrict__ Graw3,
    const float* __restrict__ g0, const float* __restrict__ g1, const float* __restrict__ g2,
    const float* __restrict__ b0, const float* __restrict__ b1, const float* __restrict__ b2,
    const float* __restrict__ e0, const float* __restrict__ e1, const float* __restrict__ e2,
    float* __restrict__ EG3) {
  __shared__ float gl[DCH * 32];
  const int b = blockIdx.x, ob = blockIdx.y, br = blockIdx.z;
  if (br == 0)
    fuse2_body<8>(b, ob, gl, Graw3, g0, b0, e0, EG3);
  else if (br == 1)
    fuse2_body<16>(b, ob, gl, Graw3 + 4096, g1, b1, e1, EG3 + 8192);
  else
    fuse2_body<32>(b, ob, gl, Graw3 + 12288, g2, b2, e2, EG3 + 24576);
}

// ---------------- yout body: Y = EG @ Qt + c -> CHWc bf16 cat ----------------
template<int K>
static __device__ void yout_body(int b, u16* egl, const float* __restrict__ EG,
    const float* __restrict__ Qt, const float* __restrict__ cres,
    u16* __restrict__ cat, int coff) {
  const int cg = blockIdx.y;
  const int t = threadIdx.x;
  const int lane = t & 63, sub = t >> 6;
  const int n = blockIdx.x * 64 + lane;
  for (int i = t; i < K * 128; i += 256) {
    int k = i >> 7, co = i & 127;
    egl[i] = f2bf(EG[((size_t)(b * 512 + cg * 128 + co)) * K + k]);
  }
  float q[K];
#pragma unroll
  for (int k = 0; k < K; ++k) q[k] = Qt[((size_t)(b * K + k)) * HWN + n];
  __syncthreads();
  const float* crow = cres + (size_t)b * 512 * HWN + n;
#pragma unroll
  for (int it = 0; it < 4; ++it) {
    int co = sub * 32 + it * 8;
    int gco = cg * 128 + co;
    float y[8];
#pragma unroll
    for (int jj = 0; jj < 8; ++jj) y[jj] = crow[(size_t)(gco + jj) * HWN];
#pragma unroll
    for (int k = 0; k < K; ++k) {
      u16x8 eg = *reinterpret_cast<const u16x8*>(&egl[k * 128 + co]);
#pragma unroll
      for (int jj = 0; jj < 8; ++jj) y[jj] = fmaf(bf2f(eg[jj]), q[k], y[jj]);
    }
    u16x8 o;
#pragma unroll
    for (int jj = 0; jj < 8; ++jj) o[jj] = f2bf(y[jj]);
    int ch = coff + gco;
    *reinterpret_cast<u16x8*>(cat +
        (((size_t)(b * 48 + (ch >> 5)) * HWN + n) * 32 + (ch & 31))) = o;
  }
}

__global__ __launch_bounds__(256) void yout3_k(const float* __restrict__ EG3,
    const float* __restrict__ Qt3, const float* __restrict__ c5,
    const float* __restrict__ c4, const float* __restrict__ c3,
    u16* __restrict__ cat) {
  __shared__ u16 egl[32 * 128];
  const int z = blockIdx.z, br = z >> 1, b = z & 1;
  if (br == 0)
    yout_body<8>(b, egl, EG3, Qt3, c5, cat, 0);
  else if (br == 1)
    yout_body<16>(b, egl, EG3 + 8192, Qt3 + 65536, c4, cat, 512);
  else
    yout_body<32>(b, egl, EG3 + 24576, Qt3 + 196608, c3, cat, 1024);
}

extern "C" void kernel_launch(void* const* d_in, const int* in_sizes, int n_in,
                              void* d_out, int out_size, void* d_ws, size_t ws_size,
                              hipStream_t stream) {
  const float* c3 = (const float*)d_in[0];
  const float* c4 = (const float*)d_in[1];
  const float* c5 = (const float*)d_in[2];
  const float* smooth_w = (const float*)d_in[24];
  const float* smg = (const float*)d_in[25];
  const float* smb = (const float*)d_in[26];
  float* dout = (float*)d_out;

  char* wsb = (char*)d_ws;
  // A: Xt3 (phase1) then cat (phase2/3)
  u16* Xt3 = (u16*)wsb;
  u16* cat = (u16*)wsb;                          // 25,165,824 B
  u16* Wb  = (u16*)(wsb + 25165824);             // 14,155,776 B
  float* pool  = (float*)(wsb + 39321600);       // 4 MB small pool
  // C @43,540,480: phase1/2 {bslab bf16 50.3M}; phase3 {sslab bf16 33.6M}
  char* C = wsb + 43540480;
  u16* bslab   = (u16*)C;
  u16* sslab   = (u16*)C;

  // pool layout (floats)
  float* Qt3  = pool;            // {0, 65536, 196608} tot 458752
  float* Qsp3 = pool + 458752;   // {0, 1024, 3072} tot 7168
  float* Mp3  = pool + 465920;   // {0, 32768, 98304} tot 229376
  float* Graw3 = pool + 723968;  // {0, 4096, 12288} tot 28672
  float* EG3  = pool + 752640;   // {0, 8192, 24576} tot 57344
  float2* AB3 = (float2*)(pool + 809984);  // {0,2048,6144} float2
  float* Ck3  = pool + 838656;   // {0,8,24}

  // ---- phase 1: batched branch convs (br0=c5/K8, br1=c4/K16, br2=c3/K32)
  t_chwc3_k<<<dim3(16, 16, 6), 256, 0, stream>>>(c5, c4, c3, Xt3);
  wpack_k<512, 256><<<dim3(256, 3), 256, 0, stream>>>(
      (const float*)d_in[17], (const float*)d_in[10], (const float*)d_in[3], Wb);
  convlds4_k<512, 256, 4, 128, 2, true><<<dim3(256, 3), 256, 0, stream>>>(Xt3, Wb, bslab);

  // ---- phase 2 (branch-batched tails; 4 slabs reduced on the fly)
  prep3_k<<<dim3(32, 3), 256, 0, stream>>>(
      (const float*)d_in[19], (const float*)d_in[12], (const float*)d_in[5],
      (const float*)d_in[18], (const float*)d_in[11], (const float*)d_in[4],
      AB3, Ck3);
  score3_k<<<dim3(64, 6), 256, 0, stream>>>(bslab, AB3, Ck3, Qt3, Qsp3);
  mmulp3_k<<<dim3(256, 8, 6), 256, 0, stream>>>(bslab, Qt3, Mp3);
  fuse13_k<<<6, 256, 0, stream>>>(Mp3, Qsp3,
      (const float*)d_in[19], (const float*)d_in[12], (const float*)d_in[5],
      (const float*)d_in[18], (const float*)d_in[11], (const float*)d_in[4],
      (const float*)d_in[20], (const float*)d_in[13], (const float*)d_in[6],
      Graw3);
  fuse23_k<<<dim3(2, 2, 3), 256, 0, stream>>>(Graw3,
      (const float*)d_in[21], (const float*)d_in[14], (const float*)d_in[7],
      (const float*)d_in[22], (const float*)d_in[15], (const float*)d_in[8],
      (const float*)d_in[23], (const float*)d_in[16], (const float*)d_in[9],
      EG3);
  yout3_k<<<dim3(64, 4, 6), 256, 0, stream>>>(EG3, Qt3, c5, c4, c3, cat);

  // ---- phase 3: smooth conv (A+B LDS, 128-co waves, bf16 slabs, SPLIT=4) + fused BN
  wpack_k<1536, 512><<<dim3(1536, 1), 256, 0, stream>>>(smooth_w, smooth_w, smooth_w, Wb);
  convlds4_k<1536, 512, 4, 128, 2, true><<<dim3(512, 1), 256, 0, stream>>>(cat, Wb, sslab);
  bnall_k<<<512, 256, 0, stream>>>(sslab, dout, smg, smb);
}

// Round 14
// 435.081 us; speedup vs baseline: 1.0191x; 1.0191x over previous
//
#include <hip/hip_runtime.h>
#include <hip/hip_bf16.h>
#include <math.h>

#define HWN 4096      // 64*64
#define DCH 256
#define EPSV 1e-5f

typedef unsigned short u16;
typedef __attribute__((ext_vector_type(8))) short short8b;   // 8 bf16 payload
typedef __attribute__((ext_vector_type(4))) float fx4;
typedef __attribute__((ext_vector_type(8))) unsigned short u16x8;

static __device__ inline u16 f2bf(float f) {
  __hip_bfloat16 h = __float2bfloat16(f);
  return *reinterpret_cast<u16*>(&h);
}
static __device__ inline float bf2f(u16 u) {
  unsigned int v = ((unsigned int)u) << 16;
  return __uint_as_float(v);
}

// ---------------- batched NCHW f32 -> CHWc bf16 (3 branches x 2 batch) ----------------
__global__ __launch_bounds__(256) void t_chwc3_k(const float* __restrict__ i0p,
    const float* __restrict__ i1p, const float* __restrict__ i2p,
    u16* __restrict__ out) {
  __shared__ float tl[32][257];
  const int p0 = blockIdx.x * 256, cic = blockIdx.y;
  const int z = blockIdx.z;             // br*2 + b
  const int br = z >> 1, b = z & 1;
  const float* in = (br == 0) ? i0p : ((br == 1) ? i1p : i2p);
  const int t = threadIdx.x;
  const float* ip = in + ((size_t)(b * 512 + cic * 32)) * HWN + p0;
#pragma unroll
  for (int r = 0; r < 32; ++r) tl[r][t] = ip[(size_t)r * HWN + t];
  __syncthreads();
  u16* op = out + ((size_t)((z * 16 + cic)) * HWN + p0 + t) * 32;
#pragma unroll
  for (int g = 0; g < 4; ++g) {
    u16x8 o;
#pragma unroll
    for (int j = 0; j < 8; ++j) o[j] = f2bf(tl[g * 8 + j][t]);
    *reinterpret_cast<u16x8*>(op + g * 8) = o;
  }
}

// ---------------- weights OIHW f32 -> fragment-packed bf16 ----------------
template<int CIN, int COUT>
__global__ __launch_bounds__(256) void wpack_k(const float* __restrict__ w0,
    const float* __restrict__ w1, const float* __restrict__ w2,
    u16* __restrict__ wp) {
  constexpr int NCIC = CIN / 32, NCOG = COUT / 16;
  const int br = blockIdx.y;
  const float* w = (br == 0) ? w0 : ((br == 1) ? w1 : w2);
  u16* wpb = wp + (size_t)br * 9 * NCIC * NCOG * 512;
  const int cog = blockIdx.x % NCOG, cic = blockIdx.x / NCOG;
  __shared__ float ws_[16 * 32 * 9];    // 18 KB
  const int t = threadIdx.x;
  const float* src = w + ((size_t)(cog * 16) * CIN + cic * 32) * 9;
  for (int i = t; i < 4608; i += 256) {
    int co = i / 288, r = i % 288;
    ws_[i] = src[(size_t)co * CIN * 9 + r];
  }
  __syncthreads();
  const size_t tapstride = (size_t)NCIC * NCOG * 512;
  const size_t base = ((size_t)cic * NCOG + cog) * 512;
#pragma unroll
  for (int tap = 0; tap < 9; ++tap) {
#pragma unroll
    for (int e0 = 0; e0 < 512; e0 += 256) {
      int e = e0 + t;
      int kg = e >> 7, m = (e >> 3) & 15, j = e & 7;
      wpb[tap * tapstride + base + e] = f2bf(ws_[m * 288 + (kg * 8 + j) * 9 + tap]);
    }
  }
}

// ---------------- split-K MFMA conv 3x3 pad 1, A+B both in LDS (R11 structure) -------
// wave = 64px (one image row) x COW co; block = 4 waves = 4 rows.
// R6 grid mapping (split slow + XCD swizzle). A: 6 halo rows, w-padded, zero-filled,
// staged once per cic. B: one ty-row of 3 taps, single-buffered, reg-prefetched.
template<int CIN, int COUT, int SPLIT, int COW, int WPE, bool BF16OUT>
__global__ __launch_bounds__(256, WPE) void convlds2_k(
    const u16* __restrict__ xt, const u16* __restrict__ wp,
    void* __restrict__ outv) {
  constexpr int NCIC = CIN / 32;
  constexpr int NCO = COUT / COW;
  constexpr int NWT = COW / 16;
  constexpr int CICPS = NCIC / SPLIT;
  constexpr int NST = CICPS * 3;
  constexpr int TAPB = COW * 32;          // u16 per B tap
  constexpr int WSH = TAPB / 4;           // u16 per wave per tap
  constexpr int RNDS = WSH / 512;         // 1KB rounds per wave per tap
  constexpr int AROW = 66 * 32;           // 2112 u16 per padded A row
  constexpr size_t OUTEL = (size_t)2 * COUT * HWN;
  __shared__ u16 bl[3 * TAPB];
  __shared__ u16 al[6 * AROW];

  const int br = blockIdx.y;
  xt += (size_t)br * 2 * NCIC * HWN * 32;
  wp += (size_t)br * 9 * NCIC * (COUT / 16) * 512;

  int g = blockIdx.x;
  const int cpx = (int)gridDim.x >> 3;
  g = (g & 7) * cpx + (g >> 3);
  const int s = g / (32 * NCO);
  const int rem = g % (32 * NCO);
  const int rt = rem / NCO;
  const int cob = (rem % NCO) * COW;

  const int wv = threadIdx.x >> 6, lane = threadIdx.x & 63;
  const int b = (rt * 4) >> 6;           // block-uniform batch
  const int h0 = (rt * 4) & 63;          // block's first image row
  const int h = h0 + wv;
  const int m = lane & 15, kg = lane >> 4;
  const int cic0 = s * CICPS;
  const int t = threadIdx.x;

  fx4 acc[4][NWT];
#pragma unroll
  for (int i = 0; i < 4; ++i)
#pragma unroll
    for (int jn = 0; jn < NWT; ++jn) acc[i][jn] = (fx4){0.f, 0.f, 0.f, 0.f};

  const u16x8 zero16 = (u16x8){0, 0, 0, 0, 0, 0, 0, 0};
  const int lds_lane = wv * WSH + lane * 8;   // per-thread B write slot

  auto stage_a = [&](int cic) {
    const u16* xc = xt + ((size_t)(b * NCIC + cic)) * HWN * 32;
#pragma unroll
    for (int r = 0; r < 6; ++r) {
      const int hl = h0 - 1 + r;
      u16x8 v = zero16;
      if ((unsigned)hl < 64u)
        v = *reinterpret_cast<const u16x8*>(xc + (size_t)hl * 2048 + t * 8);
      *reinterpret_cast<u16x8*>(&al[r * AROW + 32 + t * 8]) = v;
    }
    if (t < 48) {
      int r = t >> 3, side = (t >> 2) & 1, part = t & 3;
      *reinterpret_cast<u16x8*>(&al[r * AROW + (side ? 65 * 32 : 0) + part * 8]) = zero16;
    }
  };

  // prologue: A(cic0) + B(stage 0)
  stage_a(cic0);
  {
#pragma unroll
    for (int t3 = 0; t3 < 3; ++t3) {
      const u16* srcb = wp + (((size_t)t3 * NCIC + cic0) * (COUT / 16) + (cob >> 4)) * 512;
#pragma unroll
      for (int r = 0; r < RNDS; ++r)
        *reinterpret_cast<u16x8*>(&bl[t3 * TAPB + lds_lane + r * 512]) =
            *reinterpret_cast<const u16x8*>(srcb + lds_lane + r * 512);
    }
  }
  __syncthreads();

#pragma unroll 1
  for (int st = 0; st < NST; ++st) {
    const bool hasnext = (st + 1 < NST);
    // prefetch next stage B into registers
    u16x8 stg[3][RNDS];
    if (hasnext) {
      const int cicn = cic0 + (st + 1) / 3, tyn = (st + 1) % 3;
#pragma unroll
      for (int t3 = 0; t3 < 3; ++t3) {
        const int tap = tyn * 3 + t3;
        const u16* srcb = wp + (((size_t)tap * NCIC + cicn) * (COUT / 16) + (cob >> 4)) * 512;
#pragma unroll
        for (int r = 0; r < RNDS; ++r)
          stg[t3][r] = *reinterpret_cast<const u16x8*>(srcb + lds_lane + r * 512);
      }
    }
    // compute current stage (A and B both from LDS; no branches)
    const int ty = st % 3;
    const u16* arow = al + (wv + ty) * AROW + kg * 8;
#pragma unroll
    for (int tx = 0; tx < 3; ++tx) {
      short8b a[4];
#pragma unroll
      for (int mt = 0; mt < 4; ++mt)
        a[mt] = *reinterpret_cast<const short8b*>(arow + (mt * 16 + m + tx) * 32);
      short8b bb[NWT];
#pragma unroll
      for (int nt = 0; nt < NWT; ++nt)
        bb[nt] = *reinterpret_cast<const short8b*>(&bl[tx * TAPB + nt * 512 + lane * 8]);
#pragma unroll
      for (int mt = 0; mt < 4; ++mt)
#pragma unroll
        for (int nt = 0; nt < NWT; ++nt)
          acc[mt][nt] = __builtin_amdgcn_mfma_f32_16x16x32_bf16(a[mt], bb[nt], acc[mt][nt], 0, 0, 0);
    }
    __syncthreads();                     // all LDS reads done
    if (hasnext) {
      if (ty == 2) stage_a(cic0 + (st + 1) / 3);   // new cic: refresh A
#pragma unroll
      for (int t3 = 0; t3 < 3; ++t3)
#pragma unroll
        for (int r = 0; r < RNDS; ++r)
          *reinterpret_cast<u16x8*>(&bl[t3 * TAPB + lds_lane + r * 512]) = stg[t3][r];
      __syncthreads();                   // new A+B visible
    }
  }

#pragma unroll
  for (int mt = 0; mt < 4; ++mt)
#pragma unroll
    for (int nt = 0; nt < NWT; ++nt) {
      int co = cob + nt * 16 + m;
      size_t idx = ((size_t)(b * COUT + co)) * HWN + h * 64 + mt * 16 + kg * 4;
      if (BF16OUT) {
        u16* op = (u16*)outv + (size_t)(br * SPLIT + s) * OUTEL + idx;
        ushort4 o;
        o.x = f2bf(acc[mt][nt][0]); o.y = f2bf(acc[mt][nt][1]);
        o.z = f2bf(acc[mt][nt][2]); o.w = f2bf(acc[mt][nt][3]);
        *reinterpret_cast<ushort4*>(op) = o;
      } else {
        float* op = (float*)outv + (size_t)(br * SPLIT + s) * OUTEL + idx;
        *reinterpret_cast<fx4*>(op) = acc[mt][nt];
      }
    }
}

// ---------------- fused smooth tail: 6-slab reduce + BN2d stats + apply + relu -------
__global__ __launch_bounds__(256) void bnall_k(const u16* __restrict__ slab,
    float* __restrict__ dout, const float* __restrict__ gm,
    const float* __restrict__ bt) {
  const int o = blockIdx.x;
  const size_t el = (size_t)2 * 512 * HWN;
  const int t = threadIdx.x;
  float y[2][2][8];
  float s = 0.f, ss = 0.f;
#pragma unroll
  for (int b = 0; b < 2; ++b)
#pragma unroll
    for (int c = 0; c < 2; ++c) {
      const size_t base = ((size_t)(b * 512 + o)) * HWN + c * 2048 + t * 8;
      u16x8 v0 = *reinterpret_cast<const u16x8*>(slab + base);
      u16x8 v1 = *reinterpret_cast<const u16x8*>(slab + el + base);
      u16x8 v2 = *reinterpret_cast<const u16x8*>(slab + 2 * el + base);
      u16x8 v3 = *reinterpret_cast<const u16x8*>(slab + 3 * el + base);
      u16x8 v4 = *reinterpret_cast<const u16x8*>(slab + 4 * el + base);
      u16x8 v5 = *reinterpret_cast<const u16x8*>(slab + 5 * el + base);
#pragma unroll
      for (int j = 0; j < 8; ++j) {
        float yv = ((bf2f(v0[j]) + bf2f(v1[j])) + (bf2f(v2[j]) + bf2f(v3[j])))
                 + (bf2f(v4[j]) + bf2f(v5[j]));
        y[b][c][j] = yv; s += yv; ss = fmaf(yv, yv, ss);
      }
    }
  __shared__ float rs[4], rss[4], fin[2];
  for (int off = 32; off; off >>= 1) { s += __shfl_down(s, off); ss += __shfl_down(ss, off); }
  int lane = t & 63, wid = t >> 6;
  if (lane == 0) { rs[wid] = s; rss[wid] = ss; }
  __syncthreads();
  if (t == 0) {
    float S = rs[0] + rs[1] + rs[2] + rs[3];
    float SS = rss[0] + rss[1] + rss[2] + rss[3];
    float mean = S / (2 * HWN);
    float var = SS / (2 * HWN) - mean * mean;
    fin[0] = mean;
    fin[1] = 1.f / sqrtf(var + EPSV);
  }
  __syncthreads();
  const float mean = fin[0], giv = fin[1] * gm[o], be = bt[o];
#pragma unroll
  for (int b = 0; b < 2; ++b)
#pragma unroll
    for (int c = 0; c < 2; ++c) {
      const size_t base = ((size_t)(b * 512 + o)) * HWN + c * 2048 + t * 8;
      fx4 o0, o1;
#pragma unroll
      for (int j = 0; j < 4; ++j)
        o0[j] = fmaxf(fmaf(y[b][c][j] - mean, giv, be), 0.f);
#pragma unroll
      for (int j = 0; j < 4; ++j)
        o1[j] = fmaxf(fmaf(y[b][c][4 + j] - mean, giv, be), 0.f);
      *reinterpret_cast<fx4*>(dout + base) = o0;
      *reinterpret_cast<fx4*>(dout + base + 4) = o1;
    }
}

// ---------------- batched AB + Ck precompute ----------------
__global__ __launch_bounds__(256) void prep3_k(
    const float* __restrict__ sc0, const float* __restrict__ sc1, const float* __restrict__ sc2,
    const float* __restrict__ cw0, const float* __restrict__ cw1, const float* __restrict__ cw2,
    float2* __restrict__ AB, float* __restrict__ Ck) {
  const int br = blockIdx.y;
  const int K = 8 << br;
  const int k = blockIdx.x;
  if (k >= K) return;
  const float* sc = (br == 0) ? sc0 : ((br == 1) ? sc1 : sc2);
  const float* cw = (br == 0) ? cw0 : ((br == 1) ? cw1 : cw2);
  float2* ABb = AB + 2048 * ((1 << br) - 1);
  float* Ckb = Ck + 8 * ((1 << br) - 1);
  const int d = threadIdx.x;
  float s = sc[d * K + k];
  float a = s * s;
  float c = cw[k * DCH + d];
  ABb[d * K + k] = make_float2(a, c * a);
  float tt = c * s;
  tt = tt * tt;
  __shared__ float red[4];
  for (int off = 32; off; off >>= 1) tt += __shfl_down(tt, off);
  int lane = threadIdx.x & 63, wid = threadIdx.x >> 6;
  if (lane == 0) red[wid] = tt;
  __syncthreads();
  if (threadIdx.x == 0) Ckb[k] = red[0] + red[1] + red[2] + red[3];
}

// ---------------- score body: 2-slab reduce + scores + softmax ----------------
template<int K>
static __device__ void score_body(int b, float* sm,
    const u16* __restrict__ s0p, const u16* __restrict__ s1p,
    const float2* __restrict__ AB, const float* __restrict__ Ck,
    float* __restrict__ Qt, float* __restrict__ Qsp) {
  const int lane = threadIdx.x & 63;
  const int g = threadIdx.x >> 6;
  const int n = blockIdx.x * 64 + lane;
  const size_t bbase = ((size_t)b * DCH) * HWN + n;
  float s_[K];
#pragma unroll
  for (int k = 0; k < K; ++k) s_[k] = 0.f;
  for (int d = g * 64; d < g * 64 + 64; ++d) {
    const size_t ofs = bbase + (size_t)d * HWN;
    float xv = bf2f(s0p[ofs]) + bf2f(s1p[ofs]);
    float x2 = xv * xv;
    float xm = -2.f * xv;
    const float2* abp = AB + d * K;
#pragma unroll
    for (int k = 0; k < K; ++k) {
      float2 ab = abp[k];
      s_[k] = fmaf(x2, ab.x, s_[k]);
      s_[k] = fmaf(xm, ab.y, s_[k]);
    }
  }
  float* smr = sm + (g * 64 + lane) * (K + 1);
#pragma unroll
  for (int k = 0; k < K; ++k) smr[k] = s_[k];
  __syncthreads();
  if (g == 0) {
    const float* r0 = sm + lane * (K + 1);
    const float* r1 = sm + (64 + lane) * (K + 1);
    const float* r2 = sm + (128 + lane) * (K + 1);
    const float* r3 = sm + (192 + lane) * (K + 1);
    float mx = -1e30f;
#pragma unroll
    for (int k = 0; k < K; ++k) {
      float v = (r0[k] + r1[k]) + (r2[k] + r3[k]);
      s_[k] = -0.5f * (v + Ck[k]);
      mx = fmaxf(mx, s_[k]);
    }
    float sum = 0.f;
#pragma unroll
    for (int k = 0; k < K; ++k) { float e = expf(s_[k] - mx); s_[k] = e; sum += e; }
    float inv = 1.f / sum;
#pragma unroll
    for (int k = 0; k < K; ++k) {
      float v = s_[k] * inv;
      Qt[((size_t)(b * K + k)) * HWN + n] = v;
      for (int off = 32; off; off >>= 1) v += __shfl_down(v, off);
      if (lane == 0) Qsp[((size_t)(b * K + k)) * 64 + blockIdx.x] = v;
    }
  }
}

__global__ __launch_bounds__(256) void score3_k(const u16* __restrict__ bslab,
    const float2* __restrict__ AB3, const float* __restrict__ Ck3,
    float* __restrict__ Qt3, float* __restrict__ Qsp3) {
  __shared__ float sm[4 * 64 * 33];
  const int z = blockIdx.y, br = z >> 1, b = z & 1;
  const size_t XEL = (size_t)2 * DCH * HWN;
  const u16* s0 = bslab + (size_t)br * 2 * XEL;
  const u16* s1 = s0 + XEL;
  if (br == 0)
    score_body<8>(b, sm, s0, s1, AB3, Ck3, Qt3, Qsp3);
  else if (br == 1)
    score_body<16>(b, sm, s0, s1, AB3 + 2048, Ck3 + 8, Qt3 + 65536, Qsp3 + 1024);
  else
    score_body<32>(b, sm, s0, s1, AB3 + 6144, Ck3 + 24, Qt3 + 196608, Qsp3 + 3072);
}

// ---------------- mmul partials body (reads 2 bf16 slabs) ----------------
template<int K>
static __device__ void mmulp_body(int b, float* xs, float* pw,
    const u16* __restrict__ s0p, const u16* __restrict__ s1p,
    const float* __restrict__ Qt, float* __restrict__ Mp) {
  const int d = blockIdx.x, nch = blockIdx.y;
  const int t = threadIdx.x;
  const size_t ofs = ((size_t)(b * DCH + d)) * HWN + nch * 512 + t;
  xs[t] = bf2f(s0p[ofs]) + bf2f(s1p[ofs]);
  xs[t + 256] = bf2f(s0p[ofs + 256]) + bf2f(s1p[ofs + 256]);
  __syncthreads();
  const int lane = t & 63, wid = t >> 6;
#pragma unroll
  for (int k = 0; k < K; ++k) {
    const float* qp = Qt + ((size_t)(b * K + k)) * HWN + nch * 512;
    float s = fmaf(xs[t], qp[t], xs[t + 256] * qp[t + 256]);
    for (int off = 32; off; off >>= 1) s += __shfl_down(s, off);
    if (lane == 0) pw[wid * 33 + k] = s;
  }
  __syncthreads();
  if (t < K)
    Mp[(((size_t)(b * DCH + d)) * K + t) * 8 + nch] =
        (pw[t] + pw[33 + t]) + (pw[66 + t] + pw[99 + t]);
}

__global__ __launch_bounds__(256) void mmulp3_k(const u16* __restrict__ bslab,
    const float* __restrict__ Qt3, float* __restrict__ Mp3) {
  __shared__ float xs[512];
  __shared__ float pw[4 * 33];
  const int z = blockIdx.z, br = z >> 1, b = z & 1;
  const size_t XEL = (size_t)2 * DCH * HWN;
  const u16* s0 = bslab + (size_t)br * 2 * XEL;
  const u16* s1 = s0 + XEL;
  if (br == 0)
    mmulp_body<8>(b, xs, pw, s0, s1, Qt3, Mp3);
  else if (br == 1)
    mmulp_body<16>(b, xs, pw, s0, s1, Qt3 + 65536, Mp3 + 32768);
  else
    mmulp_body<32>(b, xs, pw, s0, s1, Qt3 + 196608, Mp3 + 98304);
}

// ---------------- fuse1 body: Qsp/Mp reduce + Z + L2norm + adj + support + relu ------
template<int K>
static __device__ void fuse1_body(int b, float* buf, const float* __restrict__ Mp,
    const float* __restrict__ Qsp, const float* __restrict__ sc,
    const float* __restrict__ cw, const float* __restrict__ Wm,
    float* __restrict__ Graw) {
  float* zl = buf;
  float* adj = zl + DCH * K;
  float* rn = adj + K * K;
  float* qsl = rn + K;
  const int t = threadIdx.x;
  if (t < K) {
    const float* qp = Qsp + ((size_t)(b * K + t)) * 64;
    float s = 0.f;
    for (int i = 0; i < 64; ++i) s += qp[i];
    qsl[t] = s;
  }
  __syncthreads();
#pragma unroll
  for (int k = 0; k < K; ++k) {
    const float* mp = Mp + (((size_t)(b * DCH + t)) * K + k) * 8;
    fx4 p0 = *reinterpret_cast<const fx4*>(mp);
    fx4 p1 = *reinterpret_cast<const fx4*>(mp + 4);
    float mm = ((p0[0] + p0[1]) + (p0[2] + p0[3])) + ((p1[0] + p1[1]) + (p1[2] + p1[3]));
    float qs = qsl[k];
    zl[t * K + k] = sc[t * K + k] * (mm - cw[k * DCH + t] * qs) / qs;
  }
  __syncthreads();
  if (t < K) {
    float s = 0.f;
    for (int i = 0; i < DCH; ++i) { float v = zl[i * K + t]; s = fmaf(v, v, s); }
    rn[t] = 1.f / sqrtf(s);
  }
  __syncthreads();
#pragma unroll
  for (int k = 0; k < K; ++k) zl[t * K + k] *= rn[k];
  __syncthreads();
  for (int p = t; p < K * K; p += 256) {
    int k = p / K, l = p % K;
    float s = 0.f;
    for (int i = 0; i < DCH; ++i) s = fmaf(zl[i * K + k], zl[i * K + l], s);
    adj[p] = s;
  }
  __syncthreads();
  float sup[K];
#pragma unroll
  for (int k = 0; k < K; ++k) sup[k] = 0.f;
  const float* wr = Wm + (size_t)t * DCH;
  for (int jj = 0; jj < DCH; ++jj) {
    float wv = wr[jj];
#pragma unroll
    for (int k = 0; k < K; ++k) sup[k] = fmaf(wv, zl[jj * K + k], sup[k]);
  }
#pragma unroll
  for (int l = 0; l < K; ++l) {
    float s = 0.f;
#pragma unroll
    for (int k = 0; k < K; ++k) s = fmaf(sup[k], adj[k * K + l], s);
    Graw[((size_t)(b * DCH + t)) * K + l] = fmaxf(s, 0.f);
  }
}

__global__ __launch_bounds__(256) void fuse13_k(const float* __restrict__ Mp3,
    const float* __restrict__ Qsp3,
    const float* __restrict__ sc0, const float* __restrict__ sc1, const float* __restrict__ sc2,
    const float* __restrict__ cw0, const float* __restrict__ cw1, const float* __restrict__ cw2,
    const float* __restrict__ wm0, const float* __restrict__ wm1, const float* __restrict__ wm2,
    float* __restrict__ Graw3) {
  __shared__ float buf[DCH * 32 + 32 * 32 + 64];
  const int z = blockIdx.x, br = z >> 1, b = z & 1;
  if (br == 0)
    fuse1_body<8>(b, buf, Mp3, Qsp3, sc0, cw0, wm0, Graw3);
  else if (br == 1)
    fuse1_body<16>(b, buf, Mp3 + 32768, Qsp3 + 1024, sc1, cw1, wm1, Graw3 + 4096);
  else
    fuse1_body<32>(b, buf, Mp3 + 98304, Qsp3 + 3072, sc2, cw2, wm2, Graw3 + 12288);
}

// ---------------- fuse2 body: BN1d (redundant per block) + EG ----------------
template<int K>
static __device__ void fuse2_body(int b, int ob, float* gl,
    const float* __restrict__ Graw, const float* __restrict__ gamma,
    const float* __restrict__ beta, const float* __restrict__ E,
    float* __restrict__ EG) {
  const int t = threadIdx.x;
  {
    const int d = t;
    float s = 0.f, ss = 0.f;
#pragma unroll
    for (int b2 = 0; b2 < 2; ++b2)
#pragma unroll
      for (int l = 0; l < K; ++l) {
        float v = Graw[((size_t)(b2 * DCH + d)) * K + l];
        s += v; ss = fmaf(v, v, ss);
      }
    const float invn = 1.f / (2 * K);
    float mean = s * invn;
    float var  = ss * invn - mean * mean;
    float giv  = gamma[d] / sqrtf(var + EPSV);
    float be   = beta[d];
#pragma unroll
    for (int l = 0; l < K; ++l) {
      float v = Graw[((size_t)(b * DCH + d)) * K + l];
      gl[d * K + l] = fmaf(v - mean, giv, be);
    }
  }
  __syncthreads();
  const int o = ob * 256 + t;
  float a[K];
#pragma unroll
  for (int k = 0; k < K; ++k) a[k] = 0.f;
  const fx4* e4 = reinterpret_cast<const fx4*>(E + (size_t)o * DCH);
  for (int d4 = 0; d4 < 64; ++d4) {
    fx4 v = e4[d4];
#pragma unroll
    for (int j = 0; j < 4; ++j) {
      float vv = v[j];
#pragma unroll
      for (int k = 0; k < K; ++k)
        a[k] = fmaf(vv, gl[(d4 * 4 + j) * K + k], a[k]);
    }
  }
#pragma unroll
  for (int k = 0; k < K; ++k)
    EG[((size_t)(b * 512 + o)) * K + k] = a[k];
}

__global__ __launch_bounds__(256) void fuse23_k(const float* __restrict__ Graw3,
    const float* __restrict__ g0, const float* __restrict__ g1, const float* __restrict__ g2,
    const float* __restrict__ b0, const float* __restrict__ b1, const float* __restrict__ b2,
    const float* __restrict__ e0, const float* __restrict__ e1, const float* __restrict__ e2,
    float* __restrict__ EG3) {
  __shared__ float gl[DCH * 32];
  const int b = blockIdx.x, ob = blockIdx.y, br = blockIdx.z;
  if (br == 0)
    fuse2_body<8>(b, ob, gl, Graw3, g0, b0, e0, EG3);
  else if (br == 1)
    fuse2_body<16>(b, ob, gl, Graw3 + 4096, g1, b1, e1, EG3 + 8192);
  else
    fuse2_body<32>(b, ob, gl, Graw3 + 12288, g2, b2, e2, EG3 + 24576);
}

// ---------------- yout body: Y = EG @ Qt + c -> CHWc bf16 cat ----------------
template<int K>
static __device__ void yout_body(int b, u16* egl, const float* __restrict__ EG,
    const float* __restrict__ Qt, const float* __restrict__ cres,
    u16* __restrict__ cat, int coff) {
  const int cg = blockIdx.y;
  const int t = threadIdx.x;
  const int lane = t & 63, sub = t >> 6;
  const int n = blockIdx.x * 64 + lane;
  for (int i = t; i < K * 128; i += 256) {
    int k = i >> 7, co = i & 127;
    egl[i] = f2bf(EG[((size_t)(b * 512 + cg * 128 + co)) * K + k]);
  }
  float q[K];
#pragma unroll
  for (int k = 0; k < K; ++k) q[k] = Qt[((size_t)(b * K + k)) * HWN + n];
  __syncthreads();
  const float* crow = cres + (size_t)b * 512 * HWN + n;
#pragma unroll
  for (int it = 0; it < 4; ++it) {
    int co = sub * 32 + it * 8;
    int gco = cg * 128 + co;
    float y[8];
#pragma unroll
    for (int jj = 0; jj < 8; ++jj) y[jj] = crow[(size_t)(gco + jj) * HWN];
#pragma unroll
    for (int k = 0; k < K; ++k) {
      u16x8 eg = *reinterpret_cast<const u16x8*>(&egl[k * 128 + co]);
#pragma unroll
      for (int jj = 0; jj < 8; ++jj) y[jj] = fmaf(bf2f(eg[jj]), q[k], y[jj]);
    }
    u16x8 o;
#pragma unroll
    for (int jj = 0; jj < 8; ++jj) o[jj] = f2bf(y[jj]);
    int ch = coff + gco;
    *reinterpret_cast<u16x8*>(cat +
        (((size_t)(b * 48 + (ch >> 5)) * HWN + n) * 32 + (ch & 31))) = o;
  }
}

__global__ __launch_bounds__(256) void yout3_k(const float* __restrict__ EG3,
    const float* __restrict__ Qt3, const float* __restrict__ c5,
    const float* __restrict__ c4, const float* __restrict__ c3,
    u16* __restrict__ cat) {
  __shared__ u16 egl[32 * 128];
  const int z = blockIdx.z, br = z >> 1, b = z & 1;
  if (br == 0)
    yout_body<8>(b, egl, EG3, Qt3, c5, cat, 0);
  else if (br == 1)
    yout_body<16>(b, egl, EG3 + 8192, Qt3 + 65536, c4, cat, 512);
  else
    yout_body<32>(b, egl, EG3 + 24576, Qt3 + 196608, c3, cat, 1024);
}

extern "C" void kernel_launch(void* const* d_in, const int* in_sizes, int n_in,
                              void* d_out, int out_size, void* d_ws, size_t ws_size,
                              hipStream_t stream) {
  const float* c3 = (const float*)d_in[0];
  const float* c4 = (const float*)d_in[1];
  const float* c5 = (const float*)d_in[2];
  const float* smooth_w = (const float*)d_in[24];
  const float* smg = (const float*)d_in[25];
  const float* smb = (const float*)d_in[26];
  float* dout = (float*)d_out;

  char* wsb = (char*)d_ws;
  // A: Xt3 (phase1) then cat (phase2/3)
  u16* Xt3 = (u16*)wsb;
  u16* cat = (u16*)wsb;                          // 25,165,824 B
  u16* Wb  = (u16*)(wsb + 25165824);             // 14,155,776 B
  float* pool  = (float*)(wsb + 39321600);       // 4 MB small pool
  // C @43,540,480: phase1/2 {bslab bf16 25.2M}; phase3 {sslab bf16 6x8.4M = 50.3M}
  char* C = wsb + 43540480;
  u16* bslab   = (u16*)C;
  u16* sslab   = (u16*)C;

  // pool layout (floats)
  float* Qt3  = pool;            // {0, 65536, 196608} tot 458752
  float* Qsp3 = pool + 458752;   // {0, 1024, 3072} tot 7168
  float* Mp3  = pool + 465920;   // {0, 32768, 98304} tot 229376
  float* Graw3 = pool + 723968;  // {0, 4096, 12288} tot 28672
  float* EG3  = pool + 752640;   // {0, 8192, 24576} tot 57344
  float2* AB3 = (float2*)(pool + 809984);  // {0,2048,6144} float2
  float* Ck3  = pool + 838656;   // {0,8,24}

  // ---- phase 1: batched branch convs (br0=c5/K8, br1=c4/K16, br2=c3/K32)
  t_chwc3_k<<<dim3(16, 16, 6), 256, 0, stream>>>(c5, c4, c3, Xt3);
  wpack_k<512, 256><<<dim3(256, 3), 256, 0, stream>>>(
      (const float*)d_in[17], (const float*)d_in[10], (const float*)d_in[3], Wb);
  convlds2_k<512, 256, 2, 64, 3, true><<<dim3(256, 3), 256, 0, stream>>>(Xt3, Wb, bslab);

  // ---- phase 2 (branch-batched tails; 2 slabs reduced on the fly)
  prep3_k<<<dim3(32, 3), 256, 0, stream>>>(
      (const float*)d_in[19], (const float*)d_in[12], (const float*)d_in[5],
      (const float*)d_in[18], (const float*)d_in[11], (const float*)d_in[4],
      AB3, Ck3);
  score3_k<<<dim3(64, 6), 256, 0, stream>>>(bslab, AB3, Ck3, Qt3, Qsp3);
  mmulp3_k<<<dim3(256, 8, 6), 256, 0, stream>>>(bslab, Qt3, Mp3);
  fuse13_k<<<6, 256, 0, stream>>>(Mp3, Qsp3,
      (const float*)d_in[19], (const float*)d_in[12], (const float*)d_in[5],
      (const float*)d_in[18], (const float*)d_in[11], (const float*)d_in[4],
      (const float*)d_in[20], (const float*)d_in[13], (const float*)d_in[6],
      Graw3);
  fuse23_k<<<dim3(2, 2, 3), 256, 0, stream>>>(Graw3,
      (const float*)d_in[21], (const float*)d_in[14], (const float*)d_in[7],
      (const float*)d_in[22], (const float*)d_in[15], (const float*)d_in[8],
      (const float*)d_in[23], (const float*)d_in[16], (const float*)d_in[9],
      EG3);
  yout3_k<<<dim3(64, 4, 6), 256, 0, stream>>>(EG3, Qt3, c5, c4, c3, cat);

  // ---- phase 3: smooth conv (A+B LDS, 128-co waves, bf16 slabs, SPLIT=6) + fused BN
  wpack_k<1536, 512><<<dim3(1536, 1), 256, 0, stream>>>(smooth_w, smooth_w, smooth_w, Wb);
  convlds2_k<1536, 512, 6, 128, 2, true><<<dim3(768, 1), 256, 0, stream>>>(cat, Wb, sslab);
  bnall_k<<<512, 256, 0, stream>>>(sslab, dout, smg, smb);
}

// Round 15
// 424.839 us; speedup vs baseline: 1.0437x; 1.0241x over previous
//
#include <hip/hip_runtime.h>
#include <hip/hip_bf16.h>
#include <math.h>

#define HWN 4096      // 64*64
#define DCH 256
#define EPSV 1e-5f

typedef unsigned short u16;
typedef __attribute__((ext_vector_type(8))) short short8b;   // 8 bf16 payload
typedef __attribute__((ext_vector_type(4))) float fx4;
typedef __attribute__((ext_vector_type(8))) unsigned short u16x8;

static __device__ inline u16 f2bf(float f) {
  __hip_bfloat16 h = __float2bfloat16(f);
  return *reinterpret_cast<u16*>(&h);
}
static __device__ inline float bf2f(u16 u) {
  unsigned int v = ((unsigned int)u) << 16;
  return __uint_as_float(v);
}

// ---------------- batched NCHW f32 -> CHWc bf16 (3 branches x 2 batch) ----------------
__global__ __launch_bounds__(256) void t_chwc3_k(const float* __restrict__ i0p,
    const float* __restrict__ i1p, const float* __restrict__ i2p,
    u16* __restrict__ out) {
  __shared__ float tl[32][257];
  const int p0 = blockIdx.x * 256, cic = blockIdx.y;
  const int z = blockIdx.z;             // br*2 + b
  const int br = z >> 1, b = z & 1;
  const float* in = (br == 0) ? i0p : ((br == 1) ? i1p : i2p);
  const int t = threadIdx.x;
  const float* ip = in + ((size_t)(b * 512 + cic * 32)) * HWN + p0;
#pragma unroll
  for (int r = 0; r < 32; ++r) tl[r][t] = ip[(size_t)r * HWN + t];
  __syncthreads();
  u16* op = out + ((size_t)((z * 16 + cic)) * HWN + p0 + t) * 32;
#pragma unroll
  for (int g = 0; g < 4; ++g) {
    u16x8 o;
#pragma unroll
    for (int j = 0; j < 8; ++j) o[j] = f2bf(tl[g * 8 + j][t]);
    *reinterpret_cast<u16x8*>(op + g * 8) = o;
  }
}

// ---------------- weights OIHW f32 -> fragment-packed bf16 ----------------
template<int CIN, int COUT>
__global__ __launch_bounds__(256) void wpack_k(const float* __restrict__ w0,
    const float* __restrict__ w1, const float* __restrict__ w2,
    u16* __restrict__ wp) {
  constexpr int NCIC = CIN / 32, NCOG = COUT / 16;
  const int br = blockIdx.y;
  const float* w = (br == 0) ? w0 : ((br == 1) ? w1 : w2);
  u16* wpb = wp + (size_t)br * 9 * NCIC * NCOG * 512;
  const int cog = blockIdx.x % NCOG, cic = blockIdx.x / NCOG;
  __shared__ float ws_[16 * 32 * 9];    // 18 KB
  const int t = threadIdx.x;
  const float* src = w + ((size_t)(cog * 16) * CIN + cic * 32) * 9;
  for (int i = t; i < 4608; i += 256) {
    int co = i / 288, r = i % 288;
    ws_[i] = src[(size_t)co * CIN * 9 + r];
  }
  __syncthreads();
  const size_t tapstride = (size_t)NCIC * NCOG * 512;
  const size_t base = ((size_t)cic * NCOG + cog) * 512;
#pragma unroll
  for (int tap = 0; tap < 9; ++tap) {
#pragma unroll
    for (int e0 = 0; e0 < 512; e0 += 256) {
      int e = e0 + t;
      int kg = e >> 7, m = (e >> 3) & 15, j = e & 7;
      wpb[tap * tapstride + base + e] = f2bf(ws_[m * 288 + (kg * 8 + j) * 9 + tap]);
    }
  }
}

// ---------------- split-K MFMA conv 3x3 pad 1, A+B both in LDS (R11 structure) -------
template<int CIN, int COUT, int SPLIT, int COW, int WPE, bool BF16OUT>
__global__ __launch_bounds__(256, WPE) void convlds2_k(
    const u16* __restrict__ xt, const u16* __restrict__ wp,
    void* __restrict__ outv) {
  constexpr int NCIC = CIN / 32;
  constexpr int NCO = COUT / COW;
  constexpr int NWT = COW / 16;
  constexpr int CICPS = NCIC / SPLIT;
  constexpr int NST = CICPS * 3;
  constexpr int TAPB = COW * 32;          // u16 per B tap
  constexpr int WSH = TAPB / 4;           // u16 per wave per tap
  constexpr int RNDS = WSH / 512;         // 1KB rounds per wave per tap
  constexpr int AROW = 66 * 32;           // 2112 u16 per padded A row
  constexpr size_t OUTEL = (size_t)2 * COUT * HWN;
  __shared__ u16 bl[3 * TAPB];
  __shared__ u16 al[6 * AROW];

  const int br = blockIdx.y;
  xt += (size_t)br * 2 * NCIC * HWN * 32;
  wp += (size_t)br * 9 * NCIC * (COUT / 16) * 512;

  int g = blockIdx.x;
  const int cpx = (int)gridDim.x >> 3;
  g = (g & 7) * cpx + (g >> 3);
  const int s = g / (32 * NCO);
  const int rem = g % (32 * NCO);
  const int rt = rem / NCO;
  const int cob = (rem % NCO) * COW;

  const int wv = threadIdx.x >> 6, lane = threadIdx.x & 63;
  const int b = (rt * 4) >> 6;           // block-uniform batch
  const int h0 = (rt * 4) & 63;          // block's first image row
  const int h = h0 + wv;
  const int m = lane & 15, kg = lane >> 4;
  const int cic0 = s * CICPS;
  const int t = threadIdx.x;

  fx4 acc[4][NWT];
#pragma unroll
  for (int i = 0; i < 4; ++i)
#pragma unroll
    for (int jn = 0; jn < NWT; ++jn) acc[i][jn] = (fx4){0.f, 0.f, 0.f, 0.f};

  const u16x8 zero16 = (u16x8){0, 0, 0, 0, 0, 0, 0, 0};
  const int lds_lane = wv * WSH + lane * 8;   // per-thread B write slot

  auto stage_a = [&](int cic) {
    const u16* xc = xt + ((size_t)(b * NCIC + cic)) * HWN * 32;
#pragma unroll
    for (int r = 0; r < 6; ++r) {
      const int hl = h0 - 1 + r;
      u16x8 v = zero16;
      if ((unsigned)hl < 64u)
        v = *reinterpret_cast<const u16x8*>(xc + (size_t)hl * 2048 + t * 8);
      *reinterpret_cast<u16x8*>(&al[r * AROW + 32 + t * 8]) = v;
    }
    if (t < 48) {
      int r = t >> 3, side = (t >> 2) & 1, part = t & 3;
      *reinterpret_cast<u16x8*>(&al[r * AROW + (side ? 65 * 32 : 0) + part * 8]) = zero16;
    }
  };

  // prologue: A(cic0) + B(stage 0)
  stage_a(cic0);
  {
#pragma unroll
    for (int t3 = 0; t3 < 3; ++t3) {
      const u16* srcb = wp + (((size_t)t3 * NCIC + cic0) * (COUT / 16) + (cob >> 4)) * 512;
#pragma unroll
      for (int r = 0; r < RNDS; ++r)
        *reinterpret_cast<u16x8*>(&bl[t3 * TAPB + lds_lane + r * 512]) =
            *reinterpret_cast<const u16x8*>(srcb + lds_lane + r * 512);
    }
  }
  __syncthreads();

#pragma unroll 1
  for (int st = 0; st < NST; ++st) {
    const bool hasnext = (st + 1 < NST);
    // prefetch next stage B into registers
    u16x8 stg[3][RNDS];
    if (hasnext) {
      const int cicn = cic0 + (st + 1) / 3, tyn = (st + 1) % 3;
#pragma unroll
      for (int t3 = 0; t3 < 3; ++t3) {
        const int tap = tyn * 3 + t3;
        const u16* srcb = wp + (((size_t)tap * NCIC + cicn) * (COUT / 16) + (cob >> 4)) * 512;
#pragma unroll
        for (int r = 0; r < RNDS; ++r)
          stg[t3][r] = *reinterpret_cast<const u16x8*>(srcb + lds_lane + r * 512);
      }
    }
    // compute current stage (A and B both from LDS; no branches)
    const int ty = st % 3;
    const u16* arow = al + (wv + ty) * AROW + kg * 8;
#pragma unroll
    for (int tx = 0; tx < 3; ++tx) {
      short8b a[4];
#pragma unroll
      for (int mt = 0; mt < 4; ++mt)
        a[mt] = *reinterpret_cast<const short8b*>(arow + (mt * 16 + m + tx) * 32);
      short8b bb[NWT];
#pragma unroll
      for (int nt = 0; nt < NWT; ++nt)
        bb[nt] = *reinterpret_cast<const short8b*>(&bl[tx * TAPB + nt * 512 + lane * 8]);
#pragma unroll
      for (int mt = 0; mt < 4; ++mt)
#pragma unroll
        for (int nt = 0; nt < NWT; ++nt)
          acc[mt][nt] = __builtin_amdgcn_mfma_f32_16x16x32_bf16(a[mt], bb[nt], acc[mt][nt], 0, 0, 0);
    }
    __syncthreads();                     // all LDS reads done
    if (hasnext) {
      if (ty == 2) stage_a(cic0 + (st + 1) / 3);   // new cic: refresh A
#pragma unroll
      for (int t3 = 0; t3 < 3; ++t3)
#pragma unroll
        for (int r = 0; r < RNDS; ++r)
          *reinterpret_cast<u16x8*>(&bl[t3 * TAPB + lds_lane + r * 512]) = stg[t3][r];
      __syncthreads();                   // new A+B visible
    }
  }

#pragma unroll
  for (int mt = 0; mt < 4; ++mt)
#pragma unroll
    for (int nt = 0; nt < NWT; ++nt) {
      int co = cob + nt * 16 + m;
      size_t idx = ((size_t)(b * COUT + co)) * HWN + h * 64 + mt * 16 + kg * 4;
      if (BF16OUT) {
        u16* op = (u16*)outv + (size_t)(br * SPLIT + s) * OUTEL + idx;
        ushort4 o;
        o.x = f2bf(acc[mt][nt][0]); o.y = f2bf(acc[mt][nt][1]);
        o.z = f2bf(acc[mt][nt][2]); o.w = f2bf(acc[mt][nt][3]);
        *reinterpret_cast<ushort4*>(op) = o;
      } else {
        float* op = (float*)outv + (size_t)(br * SPLIT + s) * OUTEL + idx;
        *reinterpret_cast<fx4*>(op) = acc[mt][nt];
      }
    }
}

// ---------------- fused smooth tail: 4-slab reduce + BN2d stats + apply + relu -------
__global__ __launch_bounds__(256) void bnall_k(const u16* __restrict__ slab,
    float* __restrict__ dout, const float* __restrict__ gm,
    const float* __restrict__ bt) {
  const int o = blockIdx.x;
  const size_t el = (size_t)2 * 512 * HWN;
  const int t = threadIdx.x;
  float y[2][2][8];
  float s = 0.f, ss = 0.f;
#pragma unroll
  for (int b = 0; b < 2; ++b)
#pragma unroll
    for (int c = 0; c < 2; ++c) {
      const size_t base = ((size_t)(b * 512 + o)) * HWN + c * 2048 + t * 8;
      u16x8 v0 = *reinterpret_cast<const u16x8*>(slab + base);
      u16x8 v1 = *reinterpret_cast<const u16x8*>(slab + el + base);
      u16x8 v2 = *reinterpret_cast<const u16x8*>(slab + 2 * el + base);
      u16x8 v3 = *reinterpret_cast<const u16x8*>(slab + 3 * el + base);
#pragma unroll
      for (int j = 0; j < 8; ++j) {
        float yv = (bf2f(v0[j]) + bf2f(v1[j])) + (bf2f(v2[j]) + bf2f(v3[j]));
        y[b][c][j] = yv; s += yv; ss = fmaf(yv, yv, ss);
      }
    }
  __shared__ float rs[4], rss[4], fin[2];
  for (int off = 32; off; off >>= 1) { s += __shfl_down(s, off); ss += __shfl_down(ss, off); }
  int lane = t & 63, wid = t >> 6;
  if (lane == 0) { rs[wid] = s; rss[wid] = ss; }
  __syncthreads();
  if (t == 0) {
    float S = rs[0] + rs[1] + rs[2] + rs[3];
    float SS = rss[0] + rss[1] + rss[2] + rss[3];
    float mean = S / (2 * HWN);
    float var = SS / (2 * HWN) - mean * mean;
    fin[0] = mean;
    fin[1] = 1.f / sqrtf(var + EPSV);
  }
  __syncthreads();
  const float mean = fin[0], giv = fin[1] * gm[o], be = bt[o];
#pragma unroll
  for (int b = 0; b < 2; ++b)
#pragma unroll
    for (int c = 0; c < 2; ++c) {
      const size_t base = ((size_t)(b * 512 + o)) * HWN + c * 2048 + t * 8;
      fx4 o0, o1;
#pragma unroll
      for (int j = 0; j < 4; ++j)
        o0[j] = fmaxf(fmaf(y[b][c][j] - mean, giv, be), 0.f);
#pragma unroll
      for (int j = 0; j < 4; ++j)
        o1[j] = fmaxf(fmaf(y[b][c][4 + j] - mean, giv, be), 0.f);
      *reinterpret_cast<fx4*>(dout + base) = o0;
      *reinterpret_cast<fx4*>(dout + base + 4) = o1;
    }
}

// ---------------- batched AB + Ck precompute ----------------
__global__ __launch_bounds__(256) void prep3_k(
    const float* __restrict__ sc0, const float* __restrict__ sc1, const float* __restrict__ sc2,
    const float* __restrict__ cw0, const float* __restrict__ cw1, const float* __restrict__ cw2,
    float2* __restrict__ AB, float* __restrict__ Ck) {
  const int br = blockIdx.y;
  const int K = 8 << br;
  const int k = blockIdx.x;
  if (k >= K) return;
  const float* sc = (br == 0) ? sc0 : ((br == 1) ? sc1 : sc2);
  const float* cw = (br == 0) ? cw0 : ((br == 1) ? cw1 : cw2);
  float2* ABb = AB + 2048 * ((1 << br) - 1);
  float* Ckb = Ck + 8 * ((1 << br) - 1);
  const int d = threadIdx.x;
  float s = sc[d * K + k];
  float a = s * s;
  float c = cw[k * DCH + d];
  ABb[d * K + k] = make_float2(a, c * a);
  float tt = c * s;
  tt = tt * tt;
  __shared__ float red[4];
  for (int off = 32; off; off >>= 1) tt += __shfl_down(tt, off);
  int lane = threadIdx.x & 63, wid = threadIdx.x >> 6;
  if (lane == 0) red[wid] = tt;
  __syncthreads();
  if (threadIdx.x == 0) Ckb[k] = red[0] + red[1] + red[2] + red[3];
}

// ---------------- score body: 2-slab reduce + scores + softmax ----------------
template<int K>
static __device__ void score_body(int b, float* sm,
    const u16* __restrict__ s0p, const u16* __restrict__ s1p,
    const float2* __restrict__ AB, const float* __restrict__ Ck,
    float* __restrict__ Qt, float* __restrict__ Qsp) {
  const int lane = threadIdx.x & 63;
  const int g = threadIdx.x >> 6;
  const int n = blockIdx.x * 64 + lane;
  const size_t bbase = ((size_t)b * DCH) * HWN + n;
  float s_[K];
#pragma unroll
  for (int k = 0; k < K; ++k) s_[k] = 0.f;
  for (int d = g * 64; d < g * 64 + 64; ++d) {
    const size_t ofs = bbase + (size_t)d * HWN;
    float xv = bf2f(s0p[ofs]) + bf2f(s1p[ofs]);
    float x2 = xv * xv;
    float xm = -2.f * xv;
    const float2* abp = AB + d * K;
#pragma unroll
    for (int k = 0; k < K; ++k) {
      float2 ab = abp[k];
      s_[k] = fmaf(x2, ab.x, s_[k]);
      s_[k] = fmaf(xm, ab.y, s_[k]);
    }
  }
  float* smr = sm + (g * 64 + lane) * (K + 1);
#pragma unroll
  for (int k = 0; k < K; ++k) smr[k] = s_[k];
  __syncthreads();
  if (g == 0) {
    const float* r0 = sm + lane * (K + 1);
    const float* r1 = sm + (64 + lane) * (K + 1);
    const float* r2 = sm + (128 + lane) * (K + 1);
    const float* r3 = sm + (192 + lane) * (K + 1);
    float mx = -1e30f;
#pragma unroll
    for (int k = 0; k < K; ++k) {
      float v = (r0[k] + r1[k]) + (r2[k] + r3[k]);
      s_[k] = -0.5f * (v + Ck[k]);
      mx = fmaxf(mx, s_[k]);
    }
    float sum = 0.f;
#pragma unroll
    for (int k = 0; k < K; ++k) { float e = expf(s_[k] - mx); s_[k] = e; sum += e; }
    float inv = 1.f / sum;
#pragma unroll
    for (int k = 0; k < K; ++k) {
      float v = s_[k] * inv;
      Qt[((size_t)(b * K + k)) * HWN + n] = v;
      for (int off = 32; off; off >>= 1) v += __shfl_down(v, off);
      if (lane == 0) Qsp[((size_t)(b * K + k)) * 64 + blockIdx.x] = v;
    }
  }
}

__global__ __launch_bounds__(256) void score3_k(const u16* __restrict__ bslab,
    const float2* __restrict__ AB3, const float* __restrict__ Ck3,
    float* __restrict__ Qt3, float* __restrict__ Qsp3) {
  __shared__ float sm[4 * 64 * 33];
  const int z = blockIdx.y, br = z >> 1, b = z & 1;
  const size_t XEL = (size_t)2 * DCH * HWN;
  const u16* s0 = bslab + (size_t)br * 2 * XEL;
  const u16* s1 = s0 + XEL;
  if (br == 0)
    score_body<8>(b, sm, s0, s1, AB3, Ck3, Qt3, Qsp3);
  else if (br == 1)
    score_body<16>(b, sm, s0, s1, AB3 + 2048, Ck3 + 8, Qt3 + 65536, Qsp3 + 1024);
  else
    score_body<32>(b, sm, s0, s1, AB3 + 6144, Ck3 + 24, Qt3 + 196608, Qsp3 + 3072);
}

// ---------------- mmul partials body, d-tiled by 4 (reads 2 bf16 slabs) ----------
template<int K>
static __device__ void mmulp_body(int b, float* xs, float* pw,
    const u16* __restrict__ s0p, const u16* __restrict__ s1p,
    const float* __restrict__ Qt, float* __restrict__ Mp) {
  const int d0 = blockIdx.x * 4, nch = blockIdx.y;
  const int t = threadIdx.x;
#pragma unroll
  for (int dd = 0; dd < 4; ++dd) {
    const size_t ofs = ((size_t)(b * DCH + d0 + dd)) * HWN + nch * 512 + t;
    xs[dd * 512 + t] = bf2f(s0p[ofs]) + bf2f(s1p[ofs]);
    xs[dd * 512 + t + 256] = bf2f(s0p[ofs + 256]) + bf2f(s1p[ofs + 256]);
  }
  __syncthreads();
  const int lane = t & 63, wid = t >> 6;
#pragma unroll
  for (int k = 0; k < K; ++k) {
    const float* qp = Qt + ((size_t)(b * K + k)) * HWN + nch * 512;
    float q0 = qp[t], q1 = qp[t + 256];
#pragma unroll
    for (int dd = 0; dd < 4; ++dd) {
      float s = fmaf(xs[dd * 512 + t], q0, xs[dd * 512 + t + 256] * q1);
      for (int off = 32; off; off >>= 1) s += __shfl_down(s, off);
      if (lane == 0) pw[(dd * 4 + wid) * 33 + k] = s;
    }
  }
  __syncthreads();
  if (t < K) {
#pragma unroll
    for (int dd = 0; dd < 4; ++dd) {
      const float* p = pw + (dd * 4) * 33;
      Mp[(((size_t)(b * DCH + d0 + dd)) * K + t) * 8 + nch] =
          (p[t] + p[33 + t]) + (p[66 + t] + p[99 + t]);
    }
  }
}

__global__ __launch_bounds__(256) void mmulp3_k(const u16* __restrict__ bslab,
    const float* __restrict__ Qt3, float* __restrict__ Mp3) {
  __shared__ float xs[4 * 512];
  __shared__ float pw[16 * 33];
  const int z = blockIdx.z, br = z >> 1, b = z & 1;
  const size_t XEL = (size_t)2 * DCH * HWN;
  const u16* s0 = bslab + (size_t)br * 2 * XEL;
  const u16* s1 = s0 + XEL;
  if (br == 0)
    mmulp_body<8>(b, xs, pw, s0, s1, Qt3, Mp3);
  else if (br == 1)
    mmulp_body<16>(b, xs, pw, s0, s1, Qt3 + 65536, Mp3 + 32768);
  else
    mmulp_body<32>(b, xs, pw, s0, s1, Qt3 + 196608, Mp3 + 98304);
}

// ---------------- fuse1 body: Qsp/Mp reduce + Z + L2norm + adj + support + relu ------
template<int K>
static __device__ void fuse1_body(int b, float* buf, const float* __restrict__ Mp,
    const float* __restrict__ Qsp, const float* __restrict__ sc,
    const float* __restrict__ cw, const float* __restrict__ Wm,
    float* __restrict__ Graw) {
  float* zl = buf;
  float* adj = zl + DCH * K;
  float* rn = adj + K * K;
  float* qsl = rn + K;
  const int t = threadIdx.x;
  if (t < K) {
    const float* qp = Qsp + ((size_t)(b * K + t)) * 64;
    float s = 0.f;
    for (int i = 0; i < 64; ++i) s += qp[i];
    qsl[t] = s;
  }
  __syncthreads();
#pragma unroll
  for (int k = 0; k < K; ++k) {
    const float* mp = Mp + (((size_t)(b * DCH + t)) * K + k) * 8;
    fx4 p0 = *reinterpret_cast<const fx4*>(mp);
    fx4 p1 = *reinterpret_cast<const fx4*>(mp + 4);
    float mm = ((p0[0] + p0[1]) + (p0[2] + p0[3])) + ((p1[0] + p1[1]) + (p1[2] + p1[3]));
    float qs = qsl[k];
    zl[t * K + k] = sc[t * K + k] * (mm - cw[k * DCH + t] * qs) / qs;
  }
  __syncthreads();
  if (t < K) {
    float s = 0.f;
    for (int i = 0; i < DCH; ++i) { float v = zl[i * K + t]; s = fmaf(v, v, s); }
    rn[t] = 1.f / sqrtf(s);
  }
  __syncthreads();
#pragma unroll
  for (int k = 0; k < K; ++k) zl[t * K + k] *= rn[k];
  __syncthreads();
  for (int p = t; p < K * K; p += 256) {
    int k = p / K, l = p % K;
    float s = 0.f;
    for (int i = 0; i < DCH; ++i) s = fmaf(zl[i * K + k], zl[i * K + l], s);
    adj[p] = s;
  }
  __syncthreads();
  float sup[K];
#pragma unroll
  for (int k = 0; k < K; ++k) sup[k] = 0.f;
  const float* wr = Wm + (size_t)t * DCH;
  for (int jj = 0; jj < DCH; ++jj) {
    float wv = wr[jj];
#pragma unroll
    for (int k = 0; k < K; ++k) sup[k] = fmaf(wv, zl[jj * K + k], sup[k]);
  }
#pragma unroll
  for (int l = 0; l < K; ++l) {
    float s = 0.f;
#pragma unroll
    for (int k = 0; k < K; ++k) s = fmaf(sup[k], adj[k * K + l], s);
    Graw[((size_t)(b * DCH + t)) * K + l] = fmaxf(s, 0.f);
  }
}

__global__ __launch_bounds__(256) void fuse13_k(const float* __restrict__ Mp3,
    const float* __restrict__ Qsp3,
    const float* __restrict__ sc0, const float* __restrict__ sc1, const float* __restrict__ sc2,
    const float* __restrict__ cw0, const float* __restrict__ cw1, const float* __restrict__ cw2,
    const float* __restrict__ wm0, const float* __restrict__ wm1, const float* __restrict__ wm2,
    float* __restrict__ Graw3) {
  __shared__ float buf[DCH * 32 + 32 * 32 + 64];
  const int z = blockIdx.x, br = z >> 1, b = z & 1;
  if (br == 0)
    fuse1_body<8>(b, buf, Mp3, Qsp3, sc0, cw0, wm0, Graw3);
  else if (br == 1)
    fuse1_body<16>(b, buf, Mp3 + 32768, Qsp3 + 1024, sc1, cw1, wm1, Graw3 + 4096);
  else
    fuse1_body<32>(b, buf, Mp3 + 98304, Qsp3 + 3072, sc2, cw2, wm2, Graw3 + 12288);
}

// ---------------- fuse2 body: BN1d (redundant per block) + EG ----------------
template<int K>
static __device__ void fuse2_body(int b, int ob, float* gl,
    const float* __restrict__ Graw, const float* __restrict__ gamma,
    const float* __restrict__ beta, const float* __restrict__ E,
    float* __restrict__ EG) {
  const int t = threadIdx.x;
  {
    const int d = t;
    float s = 0.f, ss = 0.f;
#pragma unroll
    for (int b2 = 0; b2 < 2; ++b2)
#pragma unroll
      for (int l = 0; l < K; ++l) {
        float v = Graw[((size_t)(b2 * DCH + d)) * K + l];
        s += v; ss = fmaf(v, v, ss);
      }
    const float invn = 1.f / (2 * K);
    float mean = s * invn;
    float var  = ss * invn - mean * mean;
    float giv  = gamma[d] / sqrtf(var + EPSV);
    float be   = beta[d];
#pragma unroll
    for (int l = 0; l < K; ++l) {
      float v = Graw[((size_t)(b * DCH + d)) * K + l];
      gl[d * K + l] = fmaf(v - mean, giv, be);
    }
  }
  __syncthreads();
  const int o = ob * 256 + t;
  float a[K];
#pragma unroll
  for (int k = 0; k < K; ++k) a[k] = 0.f;
  const fx4* e4 = reinterpret_cast<const fx4*>(E + (size_t)o * DCH);
  for (int d4 = 0; d4 < 64; ++d4) {
    fx4 v = e4[d4];
#pragma unroll
    for (int j = 0; j < 4; ++j) {
      float vv = v[j];
#pragma unroll
      for (int k = 0; k < K; ++k)
        a[k] = fmaf(vv, gl[(d4 * 4 + j) * K + k], a[k]);
    }
  }
#pragma unroll
  for (int k = 0; k < K; ++k)
    EG[((size_t)(b * 512 + o)) * K + k] = a[k];
}

__global__ __launch_bounds__(256) void fuse23_k(const float* __restrict__ Graw3,
    const float* __restrict__ g0, const float* __restrict__ g1, const float* __restrict__ g2,
    const float* __restrict__ b0, const float* __restrict__ b1, const float* __restrict__ b2,
    const float* __restrict__ e0, const float* __restrict__ e1, const float* __restrict__ e2,
    float* __restrict__ EG3) {
  __shared__ float gl[DCH * 32];
  const int b = blockIdx.x, ob = blockIdx.y, br = blockIdx.z;
  if (br == 0)
    fuse2_body<8>(b, ob, gl, Graw3, g0, b0, e0, EG3);
  else if (br == 1)
    fuse2_body<16>(b, ob, gl, Graw3 + 4096, g1, b1, e1, EG3 + 8192);
  else
    fuse2_body<32>(b, ob, gl, Graw3 + 12288, g2, b2, e2, EG3 + 24576);
}

// ---------------- yout body: Y = EG @ Qt + c -> CHWc bf16 cat ----------------
template<int K>
static __device__ void yout_body(int b, u16* egl, const float* __restrict__ EG,
    const float* __restrict__ Qt, const float* __restrict__ cres,
    u16* __restrict__ cat, int coff) {
  const int cg = blockIdx.y;
  const int t = threadIdx.x;
  const int lane = t & 63, sub = t >> 6;
  const int n = blockIdx.x * 64 + lane;
  for (int i = t; i < K * 128; i += 256) {
    int k = i >> 7, co = i & 127;
    egl[i] = f2bf(EG[((size_t)(b * 512 + cg * 128 + co)) * K + k]);
  }
  float q[K];
#pragma unroll
  for (int k = 0; k < K; ++k) q[k] = Qt[((size_t)(b * K + k)) * HWN + n];
  __syncthreads();
  const float* crow = cres + (size_t)b * 512 * HWN + n;
#pragma unroll
  for (int it = 0; it < 4; ++it) {
    int co = sub * 32 + it * 8;
    int gco = cg * 128 + co;
    float y[8];
#pragma unroll
    for (int jj = 0; jj < 8; ++jj) y[jj] = crow[(size_t)(gco + jj) * HWN];
#pragma unroll
    for (int k = 0; k < K; ++k) {
      u16x8 eg = *reinterpret_cast<const u16x8*>(&egl[k * 128 + co]);
#pragma unroll
      for (int jj = 0; jj < 8; ++jj) y[jj] = fmaf(bf2f(eg[jj]), q[k], y[jj]);
    }
    u16x8 o;
#pragma unroll
    for (int jj = 0; jj < 8; ++jj) o[jj] = f2bf(y[jj]);
    int ch = coff + gco;
    *reinterpret_cast<u16x8*>(cat +
        (((size_t)(b * 48 + (ch >> 5)) * HWN + n) * 32 + (ch & 31))) = o;
  }
}

__global__ __launch_bounds__(256) void yout3_k(const float* __restrict__ EG3,
    const float* __restrict__ Qt3, const float* __restrict__ c5,
    const float* __restrict__ c4, const float* __restrict__ c3,
    u16* __restrict__ cat) {
  __shared__ u16 egl[32 * 128];
  const int z = blockIdx.z, br = z >> 1, b = z & 1;
  if (br == 0)
    yout_body<8>(b, egl, EG3, Qt3, c5, cat, 0);
  else if (br == 1)
    yout_body<16>(b, egl, EG3 + 8192, Qt3 + 65536, c4, cat, 512);
  else
    yout_body<32>(b, egl, EG3 + 24576, Qt3 + 196608, c3, cat, 1024);
}

extern "C" void kernel_launch(void* const* d_in, const int* in_sizes, int n_in,
                              void* d_out, int out_size, void* d_ws, size_t ws_size,
                              hipStream_t stream) {
  const float* c3 = (const float*)d_in[0];
  const float* c4 = (const float*)d_in[1];
  const float* c5 = (const float*)d_in[2];
  const float* smooth_w = (const float*)d_in[24];
  const float* smg = (const float*)d_in[25];
  const float* smb = (const float*)d_in[26];
  float* dout = (float*)d_out;

  char* wsb = (char*)d_ws;
  // A: Xt3 (phase1) then cat (phase2/3)
  u16* Xt3 = (u16*)wsb;
  u16* cat = (u16*)wsb;                          // 25,165,824 B
  u16* Wb  = (u16*)(wsb + 25165824);             // 14,155,776 B
  float* pool  = (float*)(wsb + 39321600);       // 4 MB small pool
  // C @43,540,480: phase1/2 {bslab bf16 25.2M}; phase3 {sslab bf16 33.6M}
  char* C = wsb + 43540480;
  u16* bslab   = (u16*)C;
  u16* sslab   = (u16*)C;

  // pool layout (floats)
  float* Qt3  = pool;            // {0, 65536, 196608} tot 458752
  float* Qsp3 = pool + 458752;   // {0, 1024, 3072} tot 7168
  float* Mp3  = pool + 465920;   // {0, 32768, 98304} tot 229376
  float* Graw3 = pool + 723968;  // {0, 4096, 12288} tot 28672
  float* EG3  = pool + 752640;   // {0, 8192, 24576} tot 57344
  float2* AB3 = (float2*)(pool + 809984);  // {0,2048,6144} float2
  float* Ck3  = pool + 838656;   // {0,8,24}

  // ---- phase 1: batched branch convs (br0=c5/K8, br1=c4/K16, br2=c3/K32)
  t_chwc3_k<<<dim3(16, 16, 6), 256, 0, stream>>>(c5, c4, c3, Xt3);
  wpack_k<512, 256><<<dim3(256, 3), 256, 0, stream>>>(
      (const float*)d_in[17], (const float*)d_in[10], (const float*)d_in[3], Wb);
  convlds2_k<512, 256, 2, 64, 3, true><<<dim3(256, 3), 256, 0, stream>>>(Xt3, Wb, bslab);

  // ---- phase 2 (branch-batched tails; 2 slabs reduced on the fly)
  prep3_k<<<dim3(32, 3), 256, 0, stream>>>(
      (const float*)d_in[19], (const float*)d_in[12], (const float*)d_in[5],
      (const float*)d_in[18], (const float*)d_in[11], (const float*)d_in[4],
      AB3, Ck3);
  score3_k<<<dim3(64, 6), 256, 0, stream>>>(bslab, AB3, Ck3, Qt3, Qsp3);
  mmulp3_k<<<dim3(64, 8, 6), 256, 0, stream>>>(bslab, Qt3, Mp3);
  fuse13_k<<<6, 256, 0, stream>>>(Mp3, Qsp3,
      (const float*)d_in[19], (const float*)d_in[12], (const float*)d_in[5],
      (const float*)d_in[18], (const float*)d_in[11], (const float*)d_in[4],
      (const float*)d_in[20], (const float*)d_in[13], (const float*)d_in[6],
      Graw3);
  fuse23_k<<<dim3(2, 2, 3), 256, 0, stream>>>(Graw3,
      (const float*)d_in[21], (const float*)d_in[14], (const float*)d_in[7],
      (const float*)d_in[22], (const float*)d_in[15], (const float*)d_in[8],
      (const float*)d_in[23], (const float*)d_in[16], (const float*)d_in[9],
      EG3);
  yout3_k<<<dim3(64, 4, 6), 256, 0, stream>>>(EG3, Qt3, c5, c4, c3, cat);

  // ---- phase 3: smooth conv (A+B LDS, 128-co waves, bf16 slabs, SPLIT=4) + fused BN
  wpack_k<1536, 512><<<dim3(1536, 1), 256, 0, stream>>>(smooth_w, smooth_w, smooth_w, Wb);
  convlds2_k<1536, 512, 4, 128, 2, true><<<dim3(512, 1), 256, 0, stream>>>(cat, Wb, sslab);
  bnall_k<<<512, 256, 0, stream>>>(sslab, dout, smg, smb);
}

// Round 16
// 422.691 us; speedup vs baseline: 1.0490x; 1.0051x over previous
//
#include <hip/hip_runtime.h>
#include <hip/hip_bf16.h>
#include <math.h>

#define HWN 4096      // 64*64
#define DCH 256
#define EPSV 1e-5f

typedef unsigned short u16;
typedef __attribute__((ext_vector_type(8))) short short8b;   // 8 bf16 payload
typedef __attribute__((ext_vector_type(4))) float fx4;
typedef __attribute__((ext_vector_type(8))) unsigned short u16x8;

static __device__ inline u16 f2bf(float f) {
  __hip_bfloat16 h = __float2bfloat16(f);
  return *reinterpret_cast<u16*>(&h);
}
static __device__ inline float bf2f(u16 u) {
  unsigned int v = ((unsigned int)u) << 16;
  return __uint_as_float(v);
}

// ---------------- batched NCHW f32 -> CHWc bf16 (3 branches x 2 batch) ----------------
__global__ __launch_bounds__(256) void t_chwc3_k(const float* __restrict__ i0p,
    const float* __restrict__ i1p, const float* __restrict__ i2p,
    u16* __restrict__ out) {
  __shared__ float tl[32][257];
  const int p0 = blockIdx.x * 256, cic = blockIdx.y;
  const int z = blockIdx.z;             // br*2 + b
  const int br = z >> 1, b = z & 1;
  const float* in = (br == 0) ? i0p : ((br == 1) ? i1p : i2p);
  const int t = threadIdx.x;
  const float* ip = in + ((size_t)(b * 512 + cic * 32)) * HWN + p0;
#pragma unroll
  for (int r = 0; r < 32; ++r) tl[r][t] = ip[(size_t)r * HWN + t];
  __syncthreads();
  u16* op = out + ((size_t)((z * 16 + cic)) * HWN + p0 + t) * 32;
#pragma unroll
  for (int g = 0; g < 4; ++g) {
    u16x8 o;
#pragma unroll
    for (int j = 0; j < 8; ++j) o[j] = f2bf(tl[g * 8 + j][t]);
    *reinterpret_cast<u16x8*>(op + g * 8) = o;
  }
}

// ---------------- weights OIHW f32 -> fragment-packed bf16 ----------------
template<int CIN, int COUT>
__global__ __launch_bounds__(256) void wpack_k(const float* __restrict__ w0,
    const float* __restrict__ w1, const float* __restrict__ w2,
    u16* __restrict__ wp) {
  constexpr int NCIC = CIN / 32, NCOG = COUT / 16;
  const int br = blockIdx.y;
  const float* w = (br == 0) ? w0 : ((br == 1) ? w1 : w2);
  u16* wpb = wp + (size_t)br * 9 * NCIC * NCOG * 512;
  const int cog = blockIdx.x % NCOG, cic = blockIdx.x / NCOG;
  __shared__ float ws_[16 * 32 * 9];    // 18 KB
  const int t = threadIdx.x;
  const float* src = w + ((size_t)(cog * 16) * CIN + cic * 32) * 9;
  for (int i = t; i < 4608; i += 256) {
    int co = i / 288, r = i % 288;
    ws_[i] = src[(size_t)co * CIN * 9 + r];
  }
  __syncthreads();
  const size_t tapstride = (size_t)NCIC * NCOG * 512;
  const size_t base = ((size_t)cic * NCOG + cog) * 512;
#pragma unroll
  for (int tap = 0; tap < 9; ++tap) {
#pragma unroll
    for (int e0 = 0; e0 < 512; e0 += 256) {
      int e = e0 + t;
      int kg = e >> 7, m = (e >> 3) & 15, j = e & 7;
      wpb[tap * tapstride + base + e] = f2bf(ws_[m * 288 + (kg * 8 + j) * 9 + tap]);
    }
  }
}

// ---------------- split-K MFMA conv 3x3 pad 1, A+B in LDS, B double-buffered ---------
// wave = 64px (one image row) x COW co; block = 4 waves = 4 rows.
// R6 grid mapping. A: 6 halo rows, single-buffered, refreshed synchronously on cic
// boundary. B: one ty-row of 3 taps, DOUBLE-buffered -> ONE barrier per stage
// (two on cic boundaries only).
template<int CIN, int COUT, int SPLIT, int COW, int WPE, bool BF16OUT>
__global__ __launch_bounds__(256, WPE) void convlds5_k(
    const u16* __restrict__ xt, const u16* __restrict__ wp,
    void* __restrict__ outv) {
  constexpr int NCIC = CIN / 32;
  constexpr int NCO = COUT / COW;
  constexpr int NWT = COW / 16;
  constexpr int CICPS = NCIC / SPLIT;
  constexpr int NST = CICPS * 3;
  constexpr int TAPB = COW * 32;          // u16 per B tap
  constexpr int WSH = TAPB / 4;           // u16 per wave per tap
  constexpr int RNDS = WSH / 512;         // 1KB rounds per wave per tap
  constexpr int AROW = 66 * 32;           // 2112 u16 per padded A row
  constexpr size_t OUTEL = (size_t)2 * COUT * HWN;
  __shared__ u16 bl[2][3 * TAPB];
  __shared__ u16 al[6 * AROW];

  const int br = blockIdx.y;
  xt += (size_t)br * 2 * NCIC * HWN * 32;
  wp += (size_t)br * 9 * NCIC * (COUT / 16) * 512;

  int g = blockIdx.x;
  const int cpx = (int)gridDim.x >> 3;
  g = (g & 7) * cpx + (g >> 3);
  const int s = g / (32 * NCO);
  const int rem = g % (32 * NCO);
  const int rt = rem / NCO;
  const int cob = (rem % NCO) * COW;

  const int wv = threadIdx.x >> 6, lane = threadIdx.x & 63;
  const int b = (rt * 4) >> 6;           // block-uniform batch
  const int h0 = (rt * 4) & 63;          // block's first image row
  const int h = h0 + wv;
  const int m = lane & 15, kg = lane >> 4;
  const int cic0 = s * CICPS;
  const int t = threadIdx.x;

  fx4 acc[4][NWT];
#pragma unroll
  for (int i = 0; i < 4; ++i)
#pragma unroll
    for (int jn = 0; jn < NWT; ++jn) acc[i][jn] = (fx4){0.f, 0.f, 0.f, 0.f};

  const u16x8 zero16 = (u16x8){0, 0, 0, 0, 0, 0, 0, 0};
  const int lds_lane = wv * WSH + lane * 8;   // per-thread B write slot

  auto stage_a = [&](int cic) {
    const u16* xc = xt + ((size_t)(b * NCIC + cic)) * HWN * 32;
#pragma unroll
    for (int r = 0; r < 6; ++r) {
      const int hl = h0 - 1 + r;
      u16x8 v = zero16;
      if ((unsigned)hl < 64u)
        v = *reinterpret_cast<const u16x8*>(xc + (size_t)hl * 2048 + t * 8);
      *reinterpret_cast<u16x8*>(&al[r * AROW + 32 + t * 8]) = v;
    }
    if (t < 48) {
      int r = t >> 3, side = (t >> 2) & 1, part = t & 3;
      *reinterpret_cast<u16x8*>(&al[r * AROW + (side ? 65 * 32 : 0) + part * 8]) = zero16;
    }
  };

  // prologue: A(cic0) + B(stage 0) into bl[0]
  stage_a(cic0);
  {
#pragma unroll
    for (int t3 = 0; t3 < 3; ++t3) {
      const u16* srcb = wp + (((size_t)t3 * NCIC + cic0) * (COUT / 16) + (cob >> 4)) * 512;
#pragma unroll
      for (int r = 0; r < RNDS; ++r)
        *reinterpret_cast<u16x8*>(&bl[0][t3 * TAPB + lds_lane + r * 512]) =
            *reinterpret_cast<const u16x8*>(srcb + lds_lane + r * 512);
    }
  }
  __syncthreads();

#pragma unroll 1
  for (int st = 0; st < NST; ++st) {
    const int cur = st & 1;
    const bool hasnext = (st + 1 < NST);
    const int ty = st % 3;
    const bool newcic = hasnext && (ty == 2);
    // prefetch next stage B into registers
    u16x8 stg[3][RNDS];
    if (hasnext) {
      const int cicn = cic0 + (st + 1) / 3, tyn = (st + 1) % 3;
#pragma unroll
      for (int t3 = 0; t3 < 3; ++t3) {
        const int tap = tyn * 3 + t3;
        const u16* srcb = wp + (((size_t)tap * NCIC + cicn) * (COUT / 16) + (cob >> 4)) * 512;
#pragma unroll
        for (int r = 0; r < RNDS; ++r)
          stg[t3][r] = *reinterpret_cast<const u16x8*>(srcb + lds_lane + r * 512);
      }
    }
    // compute current stage (A and B both from LDS; reads bl[cur])
    const u16* arow = al + (wv + ty) * AROW + kg * 8;
#pragma unroll
    for (int tx = 0; tx < 3; ++tx) {
      short8b a[4];
#pragma unroll
      for (int mt = 0; mt < 4; ++mt)
        a[mt] = *reinterpret_cast<const short8b*>(arow + (mt * 16 + m + tx) * 32);
      short8b bb[NWT];
#pragma unroll
      for (int nt = 0; nt < NWT; ++nt)
        bb[nt] = *reinterpret_cast<const short8b*>(&bl[cur][tx * TAPB + nt * 512 + lane * 8]);
#pragma unroll
      for (int mt = 0; mt < 4; ++mt)
#pragma unroll
        for (int nt = 0; nt < NWT; ++nt)
          acc[mt][nt] = __builtin_amdgcn_mfma_f32_16x16x32_bf16(a[mt], bb[nt], acc[mt][nt], 0, 0, 0);
    }
    if (hasnext) {
      if (newcic) {
        __syncthreads();                 // all al reads done
        stage_a(cic0 + (st + 1) / 3);    // refresh A (synchronous, as R15)
      }
      // write prefetched B into the other buffer (no reader since last barrier)
#pragma unroll
      for (int t3 = 0; t3 < 3; ++t3)
#pragma unroll
        for (int r = 0; r < RNDS; ++r)
          *reinterpret_cast<u16x8*>(&bl[cur ^ 1][t3 * TAPB + lds_lane + r * 512]) = stg[t3][r];
      __syncthreads();                   // new A+B visible
    }
  }

#pragma unroll
  for (int mt = 0; mt < 4; ++mt)
#pragma unroll
    for (int nt = 0; nt < NWT; ++nt) {
      int co = cob + nt * 16 + m;
      size_t idx = ((size_t)(b * COUT + co)) * HWN + h * 64 + mt * 16 + kg * 4;
      if (BF16OUT) {
        u16* op = (u16*)outv + (size_t)(br * SPLIT + s) * OUTEL + idx;
        ushort4 o;
        o.x = f2bf(acc[mt][nt][0]); o.y = f2bf(acc[mt][nt][1]);
        o.z = f2bf(acc[mt][nt][2]); o.w = f2bf(acc[mt][nt][3]);
        *reinterpret_cast<ushort4*>(op) = o;
      } else {
        float* op = (float*)outv + (size_t)(br * SPLIT + s) * OUTEL + idx;
        *reinterpret_cast<fx4*>(op) = acc[mt][nt];
      }
    }
}

// ---------------- fused smooth tail: 4-slab reduce + BN2d stats + apply + relu -------
__global__ __launch_bounds__(256) void bnall_k(const u16* __restrict__ slab,
    float* __restrict__ dout, const float* __restrict__ gm,
    const float* __restrict__ bt) {
  const int o = blockIdx.x;
  const size_t el = (size_t)2 * 512 * HWN;
  const int t = threadIdx.x;
  float y[2][2][8];
  float s = 0.f, ss = 0.f;
#pragma unroll
  for (int b = 0; b < 2; ++b)
#pragma unroll
    for (int c = 0; c < 2; ++c) {
      const size_t base = ((size_t)(b * 512 + o)) * HWN + c * 2048 + t * 8;
      u16x8 v0 = *reinterpret_cast<const u16x8*>(slab + base);
      u16x8 v1 = *reinterpret_cast<const u16x8*>(slab + el + base);
      u16x8 v2 = *reinterpret_cast<const u16x8*>(slab + 2 * el + base);
      u16x8 v3 = *reinterpret_cast<const u16x8*>(slab + 3 * el + base);
#pragma unroll
      for (int j = 0; j < 8; ++j) {
        float yv = (bf2f(v0[j]) + bf2f(v1[j])) + (bf2f(v2[j]) + bf2f(v3[j]));
        y[b][c][j] = yv; s += yv; ss = fmaf(yv, yv, ss);
      }
    }
  __shared__ float rs[4], rss[4], fin[2];
  for (int off = 32; off; off >>= 1) { s += __shfl_down(s, off); ss += __shfl_down(ss, off); }
  int lane = t & 63, wid = t >> 6;
  if (lane == 0) { rs[wid] = s; rss[wid] = ss; }
  __syncthreads();
  if (t == 0) {
    float S = rs[0] + rs[1] + rs[2] + rs[3];
    float SS = rss[0] + rss[1] + rss[2] + rss[3];
    float mean = S / (2 * HWN);
    float var = SS / (2 * HWN) - mean * mean;
    fin[0] = mean;
    fin[1] = 1.f / sqrtf(var + EPSV);
  }
  __syncthreads();
  const float mean = fin[0], giv = fin[1] * gm[o], be = bt[o];
#pragma unroll
  for (int b = 0; b < 2; ++b)
#pragma unroll
    for (int c = 0; c < 2; ++c) {
      const size_t base = ((size_t)(b * 512 + o)) * HWN + c * 2048 + t * 8;
      fx4 o0, o1;
#pragma unroll
      for (int j = 0; j < 4; ++j)
        o0[j] = fmaxf(fmaf(y[b][c][j] - mean, giv, be), 0.f);
#pragma unroll
      for (int j = 0; j < 4; ++j)
        o1[j] = fmaxf(fmaf(y[b][c][4 + j] - mean, giv, be), 0.f);
      *reinterpret_cast<fx4*>(dout + base) = o0;
      *reinterpret_cast<fx4*>(dout + base + 4) = o1;
    }
}

// ---------------- batched AB + Ck precompute ----------------
__global__ __launch_bounds__(256) void prep3_k(
    const float* __restrict__ sc0, const float* __restrict__ sc1, const float* __restrict__ sc2,
    const float* __restrict__ cw0, const float* __restrict__ cw1, const float* __restrict__ cw2,
    float2* __restrict__ AB, float* __restrict__ Ck) {
  const int br = blockIdx.y;
  const int K = 8 << br;
  const int k = blockIdx.x;
  if (k >= K) return;
  const float* sc = (br == 0) ? sc0 : ((br == 1) ? sc1 : sc2);
  const float* cw = (br == 0) ? cw0 : ((br == 1) ? cw1 : cw2);
  float2* ABb = AB + 2048 * ((1 << br) - 1);
  float* Ckb = Ck + 8 * ((1 << br) - 1);
  const int d = threadIdx.x;
  float s = sc[d * K + k];
  float a = s * s;
  float c = cw[k * DCH + d];
  ABb[d * K + k] = make_float2(a, c * a);
  float tt = c * s;
  tt = tt * tt;
  __shared__ float red[4];
  for (int off = 32; off; off >>= 1) tt += __shfl_down(tt, off);
  int lane = threadIdx.x & 63, wid = threadIdx.x >> 6;
  if (lane == 0) red[wid] = tt;
  __syncthreads();
  if (threadIdx.x == 0) Ckb[k] = red[0] + red[1] + red[2] + red[3];
}

// ---------------- score body: 2-slab reduce + scores + softmax ----------------
template<int K>
static __device__ void score_body(int b, float* sm,
    const u16* __restrict__ s0p, const u16* __restrict__ s1p,
    const float2* __restrict__ AB, const float* __restrict__ Ck,
    float* __restrict__ Qt, float* __restrict__ Qsp) {
  const int lane = threadIdx.x & 63;
  const int g = threadIdx.x >> 6;
  const int n = blockIdx.x * 64 + lane;
  const size_t bbase = ((size_t)b * DCH) * HWN + n;
  float s_[K];
#pragma unroll
  for (int k = 0; k < K; ++k) s_[k] = 0.f;
  for (int d = g * 64; d < g * 64 + 64; ++d) {
    const size_t ofs = bbase + (size_t)d * HWN;
    float xv = bf2f(s0p[ofs]) + bf2f(s1p[ofs]);
    float x2 = xv * xv;
    float xm = -2.f * xv;
    const float2* abp = AB + d * K;
#pragma unroll
    for (int k = 0; k < K; ++k) {
      float2 ab = abp[k];
      s_[k] = fmaf(x2, ab.x, s_[k]);
      s_[k] = fmaf(xm, ab.y, s_[k]);
    }
  }
  float* smr = sm + (g * 64 + lane) * (K + 1);
#pragma unroll
  for (int k = 0; k < K; ++k) smr[k] = s_[k];
  __syncthreads();
  if (g == 0) {
    const float* r0 = sm + lane * (K + 1);
    const float* r1 = sm + (64 + lane) * (K + 1);
    const float* r2 = sm + (128 + lane) * (K + 1);
    const float* r3 = sm + (192 + lane) * (K + 1);
    float mx = -1e30f;
#pragma unroll
    for (int k = 0; k < K; ++k) {
      float v = (r0[k] + r1[k]) + (r2[k] + r3[k]);
      s_[k] = -0.5f * (v + Ck[k]);
      mx = fmaxf(mx, s_[k]);
    }
    float sum = 0.f;
#pragma unroll
    for (int k = 0; k < K; ++k) { float e = expf(s_[k] - mx); s_[k] = e; sum += e; }
    float inv = 1.f / sum;
#pragma unroll
    for (int k = 0; k < K; ++k) {
      float v = s_[k] * inv;
      Qt[((size_t)(b * K + k)) * HWN + n] = v;
      for (int off = 32; off; off >>= 1) v += __shfl_down(v, off);
      if (lane == 0) Qsp[((size_t)(b * K + k)) * 64 + blockIdx.x] = v;
    }
  }
}

__global__ __launch_bounds__(256) void score3_k(const u16* __restrict__ bslab,
    const float2* __restrict__ AB3, const float* __restrict__ Ck3,
    float* __restrict__ Qt3, float* __restrict__ Qsp3) {
  __shared__ float sm[4 * 64 * 33];
  const int z = blockIdx.y, br = z >> 1, b = z & 1;
  const size_t XEL = (size_t)2 * DCH * HWN;
  const u16* s0 = bslab + (size_t)br * 2 * XEL;
  const u16* s1 = s0 + XEL;
  if (br == 0)
    score_body<8>(b, sm, s0, s1, AB3, Ck3, Qt3, Qsp3);
  else if (br == 1)
    score_body<16>(b, sm, s0, s1, AB3 + 2048, Ck3 + 8, Qt3 + 65536, Qsp3 + 1024);
  else
    score_body<32>(b, sm, s0, s1, AB3 + 6144, Ck3 + 24, Qt3 + 196608, Qsp3 + 3072);
}

// ---------------- mmul partials body, d-tiled by 4 (reads 2 bf16 slabs) ----------
template<int K>
static __device__ void mmulp_body(int b, float* xs, float* pw,
    const u16* __restrict__ s0p, const u16* __restrict__ s1p,
    const float* __restrict__ Qt, float* __restrict__ Mp) {
  const int d0 = blockIdx.x * 4, nch = blockIdx.y;
  const int t = threadIdx.x;
#pragma unroll
  for (int dd = 0; dd < 4; ++dd) {
    const size_t ofs = ((size_t)(b * DCH + d0 + dd)) * HWN + nch * 512 + t;
    xs[dd * 512 + t] = bf2f(s0p[ofs]) + bf2f(s1p[ofs]);
    xs[dd * 512 + t + 256] = bf2f(s0p[ofs + 256]) + bf2f(s1p[ofs + 256]);
  }
  __syncthreads();
  const int lane = t & 63, wid = t >> 6;
#pragma unroll
  for (int k = 0; k < K; ++k) {
    const float* qp = Qt + ((size_t)(b * K + k)) * HWN + nch * 512;
    float q0 = qp[t], q1 = qp[t + 256];
#pragma unroll
    for (int dd = 0; dd < 4; ++dd) {
      float s = fmaf(xs[dd * 512 + t], q0, xs[dd * 512 + t + 256] * q1);
      for (int off = 32; off; off >>= 1) s += __shfl_down(s, off);
      if (lane == 0) pw[(dd * 4 + wid) * 33 + k] = s;
    }
  }
  __syncthreads();
  if (t < K) {
#pragma unroll
    for (int dd = 0; dd < 4; ++dd) {
      const float* p = pw + (dd * 4) * 33;
      Mp[(((size_t)(b * DCH + d0 + dd)) * K + t) * 8 + nch] =
          (p[t] + p[33 + t]) + (p[66 + t] + p[99 + t]);
    }
  }
}

__global__ __launch_bounds__(256) void mmulp3_k(const u16* __restrict__ bslab,
    const float* __restrict__ Qt3, float* __restrict__ Mp3) {
  __shared__ float xs[4 * 512];
  __shared__ float pw[16 * 33];
  const int z = blockIdx.z, br = z >> 1, b = z & 1;
  const size_t XEL = (size_t)2 * DCH * HWN;
  const u16* s0 = bslab + (size_t)br * 2 * XEL;
  const u16* s1 = s0 + XEL;
  if (br == 0)
    mmulp_body<8>(b, xs, pw, s0, s1, Qt3, Mp3);
  else if (br == 1)
    mmulp_body<16>(b, xs, pw, s0, s1, Qt3 + 65536, Mp3 + 32768);
  else
    mmulp_body<32>(b, xs, pw, s0, s1, Qt3 + 196608, Mp3 + 98304);
}

// ---------------- fuse1 body: Qsp/Mp reduce + Z + L2norm + adj + support + relu ------
template<int K>
static __device__ void fuse1_body(int b, float* buf, const float* __restrict__ Mp,
    const float* __restrict__ Qsp, const float* __restrict__ sc,
    const float* __restrict__ cw, const float* __restrict__ Wm,
    float* __restrict__ Graw) {
  float* zl = buf;
  float* adj = zl + DCH * K;
  float* rn = adj + K * K;
  float* qsl = rn + K;
  const int t = threadIdx.x;
  if (t < K) {
    const float* qp = Qsp + ((size_t)(b * K + t)) * 64;
    float s = 0.f;
    for (int i = 0; i < 64; ++i) s += qp[i];
    qsl[t] = s;
  }
  __syncthreads();
#pragma unroll
  for (int k = 0; k < K; ++k) {
    const float* mp = Mp + (((size_t)(b * DCH + t)) * K + k) * 8;
    fx4 p0 = *reinterpret_cast<const fx4*>(mp);
    fx4 p1 = *reinterpret_cast<const fx4*>(mp + 4);
    float mm = ((p0[0] + p0[1]) + (p0[2] + p0[3])) + ((p1[0] + p1[1]) + (p1[2] + p1[3]));
    float qs = qsl[k];
    zl[t * K + k] = sc[t * K + k] * (mm - cw[k * DCH + t] * qs) / qs;
  }
  __syncthreads();
  if (t < K) {
    float s = 0.f;
    for (int i = 0; i < DCH; ++i) { float v = zl[i * K + t]; s = fmaf(v, v, s); }
    rn[t] = 1.f / sqrtf(s);
  }
  __syncthreads();
#pragma unroll
  for (int k = 0; k < K; ++k) zl[t * K + k] *= rn[k];
  __syncthreads();
  for (int p = t; p < K * K; p += 256) {
    int k = p / K, l = p % K;
    float s = 0.f;
    for (int i = 0; i < DCH; ++i) s = fmaf(zl[i * K + k], zl[i * K + l], s);
    adj[p] = s;
  }
  __syncthreads();
  float sup[K];
#pragma unroll
  for (int k = 0; k < K; ++k) sup[k] = 0.f;
  const float* wr = Wm + (size_t)t * DCH;
  for (int jj = 0; jj < DCH; ++jj) {
    float wv = wr[jj];
#pragma unroll
    for (int k = 0; k < K; ++k) sup[k] = fmaf(wv, zl[jj * K + k], sup[k]);
  }
#pragma unroll
  for (int l = 0; l < K; ++l) {
    float s = 0.f;
#pragma unroll
    for (int k = 0; k < K; ++k) s = fmaf(sup[k], adj[k * K + l], s);
    Graw[((size_t)(b * DCH + t)) * K + l] = fmaxf(s, 0.f);
  }
}

__global__ __launch_bounds__(256) void fuse13_k(const float* __restrict__ Mp3,
    const float* __restrict__ Qsp3,
    const float* __restrict__ sc0, const float* __restrict__ sc1, const float* __restrict__ sc2,
    const float* __restrict__ cw0, const float* __restrict__ cw1, const float* __restrict__ cw2,
    const float* __restrict__ wm0, const float* __restrict__ wm1, const float* __restrict__ wm2,
    float* __restrict__ Graw3) {
  __shared__ float buf[DCH * 32 + 32 * 32 + 64];
  const int z = blockIdx.x, br = z >> 1, b = z & 1;
  if (br == 0)
    fuse1_body<8>(b, buf, Mp3, Qsp3, sc0, cw0, wm0, Graw3);
  else if (br == 1)
    fuse1_body<16>(b, buf, Mp3 + 32768, Qsp3 + 1024, sc1, cw1, wm1, Graw3 + 4096);
  else
    fuse1_body<32>(b, buf, Mp3 + 98304, Qsp3 + 3072, sc2, cw2, wm2, Graw3 + 12288);
}

// ---------------- fuse2 body: BN1d (redundant per block) + EG ----------------
template<int K>
static __device__ void fuse2_body(int b, int ob, float* gl,
    const float* __restrict__ Graw, const float* __restrict__ gamma,
    const float* __restrict__ beta, const float* __restrict__ E,
    float* __restrict__ EG) {
  const int t = threadIdx.x;
  {
    const int d = t;
    float s = 0.f, ss = 0.f;
#pragma unroll
    for (int b2 = 0; b2 < 2; ++b2)
#pragma unroll
      for (int l = 0; l < K; ++l) {
        float v = Graw[((size_t)(b2 * DCH + d)) * K + l];
        s += v; ss = fmaf(v, v, ss);
      }
    const float invn = 1.f / (2 * K);
    float mean = s * invn;
    float var  = ss * invn - mean * mean;
    float giv  = gamma[d] / sqrtf(var + EPSV);
    float be   = beta[d];
#pragma unroll
    for (int l = 0; l < K; ++l) {
      float v = Graw[((size_t)(b * DCH + d)) * K + l];
      gl[d * K + l] = fmaf(v - mean, giv, be);
    }
  }
  __syncthreads();
  const int o = ob * 256 + t;
  float a[K];
#pragma unroll
  for (int k = 0; k < K; ++k) a[k] = 0.f;
  const fx4* e4 = reinterpret_cast<const fx4*>(E + (size_t)o * DCH);
  for (int d4 = 0; d4 < 64; ++d4) {
    fx4 v = e4[d4];
#pragma unroll
    for (int j = 0; j < 4; ++j) {
      float vv = v[j];
#pragma unroll
      for (int k = 0; k < K; ++k)
        a[k] = fmaf(vv, gl[(d4 * 4 + j) * K + k], a[k]);
    }
  }
#pragma unroll
  for (int k = 0; k < K; ++k)
    EG[((size_t)(b * 512 + o)) * K + k] = a[k];
}

__global__ __launch_bounds__(256) void fuse23_k(const float* __restrict__ Graw3,
    const float* __restrict__ g0, const float* __restrict__ g1, const float* __restrict__ g2,
    const float* __restrict__ b0, const float* __restrict__ b1, const float* __restrict__ b2,
    const float* __restrict__ e0, const float* __restrict__ e1, const float* __restrict__ e2,
    float* __restrict__ EG3) {
  __shared__ float gl[DCH * 32];
  const int b = blockIdx.x, ob = blockIdx.y, br = blockIdx.z;
  if (br == 0)
    fuse2_body<8>(b, ob, gl, Graw3, g0, b0, e0, EG3);
  else if (br == 1)
    fuse2_body<16>(b, ob, gl, Graw3 + 4096, g1, b1, e1, EG3 + 8192);
  else
    fuse2_body<32>(b, ob, gl, Graw3 + 12288, g2, b2, e2, EG3 + 24576);
}

// ---------------- yout body: Y = EG @ Qt + c -> CHWc bf16 cat ----------------
template<int K>
static __device__ void yout_body(int b, u16* egl, const float* __restrict__ EG,
    const float* __restrict__ Qt, const float* __restrict__ cres,
    u16* __restrict__ cat, int coff) {
  const int cg = blockIdx.y;
  const int t = threadIdx.x;
  const int lane = t & 63, sub = t >> 6;
  const int n = blockIdx.x * 64 + lane;
  for (int i = t; i < K * 128; i += 256) {
    int k = i >> 7, co = i & 127;
    egl[i] = f2bf(EG[((size_t)(b * 512 + cg * 128 + co)) * K + k]);
  }
  float q[K];
#pragma unroll
  for (int k = 0; k < K; ++k) q[k] = Qt[((size_t)(b * K + k)) * HWN + n];
  __syncthreads();
  const float* crow = cres + (size_t)b * 512 * HWN + n;
#pragma unroll
  for (int it = 0; it < 4; ++it) {
    int co = sub * 32 + it * 8;
    int gco = cg * 128 + co;
    float y[8];
#pragma unroll
    for (int jj = 0; jj < 8; ++jj) y[jj] = crow[(size_t)(gco + jj) * HWN];
#pragma unroll
    for (int k = 0; k < K; ++k) {
      u16x8 eg = *reinterpret_cast<const u16x8*>(&egl[k * 128 + co]);
#pragma unroll
      for (int jj = 0; jj < 8; ++jj) y[jj] = fmaf(bf2f(eg[jj]), q[k], y[jj]);
    }
    u16x8 o;
#pragma unroll
    for (int jj = 0; jj < 8; ++jj) o[jj] = f2bf(y[jj]);
    int ch = coff + gco;
    *reinterpret_cast<u16x8*>(cat +
        (((size_t)(b * 48 + (ch >> 5)) * HWN + n) * 32 + (ch & 31))) = o;
  }
}

__global__ __launch_bounds__(256) void yout3_k(const float* __restrict__ EG3,
    const float* __restrict__ Qt3, const float* __restrict__ c5,
    const float* __restrict__ c4, const float* __restrict__ c3,
    u16* __restrict__ cat) {
  __shared__ u16 egl[32 * 128];
  const int z = blockIdx.z, br = z >> 1, b = z & 1;
  if (br == 0)
    yout_body<8>(b, egl, EG3, Qt3, c5, cat, 0);
  else if (br == 1)
    yout_body<16>(b, egl, EG3 + 8192, Qt3 + 65536, c4, cat, 512);
  else
    yout_body<32>(b, egl, EG3 + 24576, Qt3 + 196608, c3, cat, 1024);
}

extern "C" void kernel_launch(void* const* d_in, const int* in_sizes, int n_in,
                              void* d_out, int out_size, void* d_ws, size_t ws_size,
                              hipStream_t stream) {
  const float* c3 = (const float*)d_in[0];
  const float* c4 = (const float*)d_in[1];
  const float* c5 = (const float*)d_in[2];
  const float* smooth_w = (const float*)d_in[24];
  const float* smg = (const float*)d_in[25];
  const float* smb = (const float*)d_in[26];
  float* dout = (float*)d_out;

  char* wsb = (char*)d_ws;
  // A: Xt3 (phase1) then cat (phase2/3)
  u16* Xt3 = (u16*)wsb;
  u16* cat = (u16*)wsb;                          // 25,165,824 B
  u16* Wb  = (u16*)(wsb + 25165824);             // 14,155,776 B
  float* pool  = (float*)(wsb + 39321600);       // 4 MB small pool
  // C @43,540,480: phase1/2 {bslab bf16 25.2M}; phase3 {sslab bf16 33.6M}
  char* C = wsb + 43540480;
  u16* bslab   = (u16*)C;
  u16* sslab   = (u16*)C;

  // pool layout (floats)
  float* Qt3  = pool;            // {0, 65536, 196608} tot 458752
  float* Qsp3 = pool + 458752;   // {0, 1024, 3072} tot 7168
  float* Mp3  = pool + 465920;   // {0, 32768, 98304} tot 229376
  float* Graw3 = pool + 723968;  // {0, 4096, 12288} tot 28672
  float* EG3  = pool + 752640;   // {0, 8192, 24576} tot 57344
  float2* AB3 = (float2*)(pool + 809984);  // {0,2048,6144} float2
  float* Ck3  = pool + 838656;   // {0,8,24}

  // ---- phase 1: batched branch convs (br0=c5/K8, br1=c4/K16, br2=c3/K32)
  t_chwc3_k<<<dim3(16, 16, 6), 256, 0, stream>>>(c5, c4, c3, Xt3);
  wpack_k<512, 256><<<dim3(256, 3), 256, 0, stream>>>(
      (const float*)d_in[17], (const float*)d_in[10], (const float*)d_in[3], Wb);
  convlds5_k<512, 256, 2, 64, 3, true><<<dim3(256, 3), 256, 0, stream>>>(Xt3, Wb, bslab);

  // ---- phase 2 (branch-batched tails; 2 slabs reduced on the fly)
  prep3_k<<<dim3(32, 3), 256, 0, stream>>>(
      (const float*)d_in[19], (const float*)d_in[12], (const float*)d_in[5],
      (const float*)d_in[18], (const float*)d_in[11], (const float*)d_in[4],
      AB3, Ck3);
  score3_k<<<dim3(64, 6), 256, 0, stream>>>(bslab, AB3, Ck3, Qt3, Qsp3);
  mmulp3_k<<<dim3(64, 8, 6), 256, 0, stream>>>(bslab, Qt3, Mp3);
  fuse13_k<<<6, 256, 0, stream>>>(Mp3, Qsp3,
      (const float*)d_in[19], (const float*)d_in[12], (const float*)d_in[5],
      (const float*)d_in[18], (const float*)d_in[11], (const float*)d_in[4],
      (const float*)d_in[20], (const float*)d_in[13], (const float*)d_in[6],
      Graw3);
  fuse23_k<<<dim3(2, 2, 3), 256, 0, stream>>>(Graw3,
      (const float*)d_in[21], (const float*)d_in[14], (const float*)d_in[7],
      (const float*)d_in[22], (const float*)d_in[15], (const float*)d_in[8],
      (const float*)d_in[23], (const float*)d_in[16], (const float*)d_in[9],
      EG3);
  yout3_k<<<dim3(64, 4, 6), 256, 0, stream>>>(EG3, Qt3, c5, c4, c3, cat);

  // ---- phase 3: smooth conv (A+B LDS, dbuf B, 128-co waves, SPLIT=4) + fused BN
  wpack_k<1536, 512><<<dim3(1536, 1), 256, 0, stream>>>(smooth_w, smooth_w, smooth_w, Wb);
  convlds5_k<1536, 512, 4, 128, 2, true><<<dim3(512, 1), 256, 0, stream>>>(cat, Wb, sslab);
  bnall_k<<<512, 256, 0, stream>>>(sslab, dout, smg, smb);
}